// Round 15
// baseline (5278.477 us; speedup 1.0000x reference)
//
#include <hip/hip_runtime.h>
#include <hip/hip_bf16.h>
#include <math.h>

// ---- static problem config ----
#define DIM    128
#define NPART  4096      // B*N particles
#define MREAL  4136      // NPART + B*K
#define MP     4224      // padded; pad rows mass 0, r=0 (splits zeroed once)
#define IB     64        // i-rows per force block
#define NIBR   65        // i-tiles covering real rows
#define JTILE  32        // j-tile
#define NJTR   130       // j-tiles covering real rows
#define ATJT   128       // first j-tile containing attractor rows (>=4096)
#define NSLICE 8
#define NROW   4136      // rows stored in apart/wsump (real rows only)
#define NITER  50
#define NPTS   1034
#define NPAIRS 534061.0
#define WR     8         // rows per k_mlp block (r15: halved -> 517 blocks, 2/CU)
#define NMLPB  517       // NROW / WR exactly

typedef __bf16 bf16x8 __attribute__((ext_vector_type(8)));
typedef __bf16 bf16x4 __attribute__((ext_vector_type(4)));
typedef float  f32x4  __attribute__((ext_vector_type(4)));

__device__ __forceinline__ f32x4 mfma16(bf16x8 a, bf16x8 b, f32x4 c) {
  return __builtin_amdgcn_mfma_f32_16x16x32_bf16(a, b, c, 0, 0, 0);
}
__device__ __forceinline__ float dot4acc(float s, float4 a, float4 b) {
  s = fmaf(a.x, b.x, s); s = fmaf(a.y, b.y, s);
  s = fmaf(a.z, b.z, s); s = fmaf(a.w, b.w, s);
  return s;
}
__device__ __forceinline__ void split3(float x, __bf16& h, __bf16& m, __bf16& l) {
  h = (__bf16)x; float t = x - (float)h;
  m = (__bf16)t; l = (__bf16)(t - (float)m);
}
// 6-product split accumulate: f32-faithful C += A*B
__device__ __forceinline__ f32x4 mm6(bf16x8 ah, bf16x8 am, bf16x8 al,
                                     bf16x8 bh, bf16x8 bm, bf16x8 bl, f32x4 c) {
  c = mfma16(ah, bh, c);
  c = mfma16(ah, bm, c);
  c = mfma16(am, bh, c);
  c = mfma16(am, bm, c);
  c = mfma16(ah, bl, c);
  c = mfma16(al, bh, c);
  return c;
}
// 4-product split accumulate: (h+m)*(h+m), rel ~2^-17
__device__ __forceinline__ f32x4 mm4(bf16x8 ah, bf16x8 am,
                                     bf16x8 bh, bf16x8 bm, f32x4 c) {
  c = mfma16(ah, bh, c);
  c = mfma16(ah, bm, c);
  c = mfma16(am, bh, c);
  c = mfma16(am, bm, c);
  return c;
}
// LDS swizzle for k_pdist (unchanged)
__device__ __forceinline__ int lds_off(int row, int slot) {
  return row * DIM + ((slot ^ ((row >> 2) & 7)) << 2);
}
// j-slot permutation baked into rjT: slot s holds j = 4*(s>>3)+(s&3)+16*((s>>2)&1)
__device__ __forceinline__ int jmap(int s) {
  return 4 * (s >> 3) + (s & 3) + 16 * ((s >> 2) & 1);
}

// ---------------- init: build padded state + sq ----------------
__global__ __launch_bounds__(256)
void k_init(const float* __restrict__ x, const float* __restrict__ ap,
            const float* __restrict__ am, const float* __restrict__ v0in,
            float* __restrict__ r, float* __restrict__ v, float* __restrict__ sq)
{
  int wid = threadIdx.x >> 6, ln = threadIdx.x & 63;
  int row = blockIdx.x * 4 + wid;
  int d0 = ln, d1 = ln + 64;
  size_t base = (size_t)row * DIM;
  float r0, r1, w0, w1;
  if (row < NPART) {
    r0 = x[base + d0]; r1 = x[base + d1]; w0 = 0.f; w1 = 0.f;
  } else if (row < MREAL) {
    int k = (row - NPART) % 10;
    r0 = ap[k * DIM + d0]; r1 = ap[k * DIM + d1];
    w0 = v0in[k * DIM + d0]; w1 = v0in[k * DIM + d1];
  } else {
    r0 = r1 = w0 = w1 = 0.f;
  }
  r[base + d0] = r0; r[base + d1] = r1;
  v[base + d0] = w0; v[base + d1] = w1;
  float n2 = r0 * r0 + r1 * r1;
  for (int mk = 1; mk < 64; mk <<= 1) n2 += __shfl_xor(n2, mk);
  if (ln == 0) { sq[row] = n2; }
}

// ---------------- wprep: split(+transpose) constant weights, ONCE ----------------
__global__ __launch_bounds__(256)
void k_wprep(const float* __restrict__ bw1, const float* __restrict__ bw2,
             const float* __restrict__ bw3, const float* __restrict__ pw1,
             const float* __restrict__ kw1,
             __bf16* __restrict__ wb1t, __bf16* __restrict__ wb2t,
             __bf16* __restrict__ wb3t, __bf16* __restrict__ wp1t,
             __bf16* __restrict__ wp1r, __bf16* __restrict__ wk1t,
             __bf16* __restrict__ wk1r)
{
  int a = blockIdx.y;
  int e = blockIdx.x * 256 + threadIdx.x;
  float val; __bf16* dst; int size;
  if (a == 0)      { size = 16384; if (e >= size) return; int n = e >> 8, k = e & 255; val = bw1[k * 64 + n];  dst = wb1t; }
  else if (a == 1) { size = 4096;  if (e >= size) return; int n = e >> 6, k = e & 63;  val = bw2[k * 64 + n];  dst = wb2t; }
  else if (a == 2) { size = 8192;  if (e >= size) return; int n = e >> 6, k = e & 63;  val = bw3[k * 128 + n]; dst = wb3t; }
  else if (a == 3) { size = 32768; if (e >= size) return; int n = e >> 7, d = e & 127; val = pw1[d * 256 + n]; dst = wp1t; }
  else if (a == 4) { size = 32768; if (e >= size) return; val = pw1[e]; dst = wp1r; }
  else if (a == 5) { size = 32768; if (e >= size) return; int n = e >> 7, d = e & 127; val = kw1[d * 256 + n]; dst = wk1t; }
  else             { size = 32768; if (e >= size) return; val = kw1[e]; dst = wk1r; }
  __bf16 h, m, l; split3(val, h, m, l);
  dst[e] = h; dst[size + e] = m; dst[2 * size + e] = l;
}

// ---------------- split: ONE-TIME full split of initial state (incl. pads) ----------------
__global__ __launch_bounds__(256)
void k_split(const float* __restrict__ r,
             __bf16* __restrict__ rh, __bf16* __restrict__ rm,
             __bf16* __restrict__ rth, __bf16* __restrict__ rtm, __bf16* __restrict__ rtl)
{
  __shared__ __bf16 hs[32][132], ms2[32][132], ls[32][132];
  const int tid = threadIdx.x;
  const int row = tid >> 3, cg = tid & 7;    // row 0..31, col-group of 16
  const int grow = blockIdx.x * 32 + row;
  const float* rp = &r[(size_t)grow * DIM + cg * 16];
  float4 f0 = *(const float4*)&rp[0];
  float4 f1 = *(const float4*)&rp[4];
  float4 f2 = *(const float4*)&rp[8];
  float4 f3 = *(const float4*)&rp[12];
  float xs[16] = {f0.x,f0.y,f0.z,f0.w, f1.x,f1.y,f1.z,f1.w,
                  f2.x,f2.y,f2.z,f2.w, f3.x,f3.y,f3.z,f3.w};
  bf16x8 hq[2], mq[2];
  #pragma unroll
  for (int e = 0; e < 16; ++e) {
    float xv = xs[e];
    __bf16 hh, mm, ll; split3(xv, hh, mm, ll);
    hq[e >> 3][e & 7] = hh; mq[e >> 3][e & 7] = mm;
    hs[row][cg * 16 + e] = hh; ms2[row][cg * 16 + e] = mm; ls[row][cg * 16 + e] = ll;
  }
  size_t ob = (size_t)grow * DIM + cg * 16;
  *(bf16x8*)&rh[ob] = hq[0]; *(bf16x8*)&rh[ob + 8] = hq[1];
  *(bf16x8*)&rm[ob] = mq[0]; *(bf16x8*)&rm[ob + 8] = mq[1];
  __syncthreads();
  for (int u = tid; u < 384; u += 256) {
    int s = u >> 7, d = u & 127;
    const __bf16* src = s == 0 ? &hs[0][0] : (s == 1 ? &ms2[0][0] : &ls[0][0]);
    __bf16 col[32];
    #pragma unroll
    for (int j = 0; j < 32; ++j) col[j] = src[j * 132 + d];
    __bf16* dst = (s == 0 ? rth : (s == 1 ? rtm : rtl)) + (size_t)d * MP + blockIdx.x * 32;
    #pragma unroll
    for (int c = 0; c < 4; ++c) {
      bf16x8 q;
      #pragma unroll
      for (int e = 0; e < 8; ++e) q[e] = col[jmap(c * 8 + e)];
      *(bf16x8*)&dst[c * 8] = q;
    }
  }
}

// ---------------- force: split-bf16 MFMA all-pairs gravity (r14 anchor, unchanged) ----------------
__global__ __launch_bounds__(256, 3)
void k_force(const __bf16* __restrict__ rh, const __bf16* __restrict__ rm,
             const __bf16* __restrict__ rth, const __bf16* __restrict__ rtm,
             const __bf16* __restrict__ rtl,
             const float* __restrict__ sq, const float* __restrict__ am,
             float* __restrict__ apart, float* __restrict__ wsump)
{
  __shared__ __align__(16) __bf16 rjRM[2][JTILE][136];  // h,m row-major (S A-operand)
  __shared__ __align__(16) __bf16 rjT[3][DIM][40];      // h,m,l transposed, j-permuted
  __shared__ float sqi_s[IB], sqj_s[JTILE], mj_s[JTILE];

  const int tid = threadIdx.x;
  const int wv = tid >> 6, lane = tid & 63;
  const int lq = lane >> 4, lr = lane & 15;
  const int slice = blockIdx.x;            // XCD = flat%8 = slice
  const int bi0 = blockIdx.y * IB;

  if (tid < IB) sqi_s[tid] = sq[bi0 + tid];

  // staging decode (fixed per thread)
  const int u1 = tid + 256;
  const int sr0 = tid >> 4, sc0 = tid & 15;     // rjRM half 0
  const int sr1 = u1 >> 4,  sc1 = u1 & 15;      // rjRM half 1
  const int td0 = tid >> 2, te0 = tid & 3;      // rjT half 0 (d 0..63)
  const int td1 = u1 >> 2,  te1 = u1 & 3;       // rjT half 1 (d 64..127)

  bf16x8 pr[10];
  float psqj = 0.f, pmj = 0.f;

  auto LOADT = [&](int jt) {
    size_t ga0 = (size_t)(jt * JTILE + sr0) * DIM + sc0 * 8;
    size_t ga1 = (size_t)(jt * JTILE + sr1) * DIM + sc1 * 8;
    pr[0] = *(const bf16x8*)&rh[ga0];  pr[1] = *(const bf16x8*)&rm[ga0];
    pr[2] = *(const bf16x8*)&rh[ga1];  pr[3] = *(const bf16x8*)&rm[ga1];
    size_t gb0 = (size_t)td0 * MP + jt * JTILE + te0 * 8;
    size_t gb1 = (size_t)td1 * MP + jt * JTILE + te1 * 8;
    pr[4] = *(const bf16x8*)&rth[gb0]; pr[5] = *(const bf16x8*)&rtm[gb0];
    pr[6] = *(const bf16x8*)&rtl[gb0]; pr[7] = *(const bf16x8*)&rth[gb1];
    pr[8] = *(const bf16x8*)&rtm[gb1]; pr[9] = *(const bf16x8*)&rtl[gb1];
    if (tid < JTILE) {
      int gj = jt * JTILE + tid;
      psqj = sq[gj];
      pmj = gj < NPART ? 0.1f : (gj < MREAL ? am[(gj - NPART) % 10] : 0.f);
    }
  };
  auto STORET = [&]() {
    *(bf16x8*)&rjRM[0][sr0][sc0 * 8] = pr[0];
    *(bf16x8*)&rjRM[1][sr0][sc0 * 8] = pr[1];
    *(bf16x8*)&rjRM[0][sr1][sc1 * 8] = pr[2];
    *(bf16x8*)&rjRM[1][sr1][sc1 * 8] = pr[3];
    *(bf16x8*)&rjT[0][td0][te0 * 8] = pr[4];
    *(bf16x8*)&rjT[1][td0][te0 * 8] = pr[5];
    *(bf16x8*)&rjT[2][td0][te0 * 8] = pr[6];
    *(bf16x8*)&rjT[0][td1][te1 * 8] = pr[7];
    *(bf16x8*)&rjT[1][td1][te1 * 8] = pr[8];
    *(bf16x8*)&rjT[2][td1][te1 * 8] = pr[9];
    if (tid < JTILE) { sqj_s[tid] = psqj; mj_s[tid] = pmj; }
  };

  // i-fragments (16 rows per wave), h,m splits (S is 4-product)
  bf16x8 riH[4], riM[4];
  {
    int gi = bi0 + wv * 16 + lr;
    const __bf16* ph = &rh[(size_t)gi * DIM];
    const __bf16* pm = &rm[(size_t)gi * DIM];
    #pragma unroll
    for (int kc = 0; kc < 4; ++kc) {
      riH[kc] = *(const bf16x8*)&ph[kc * 32 + lq * 8];
      riM[kc] = *(const bf16x8*)&pm[kc * 32 + lq * 8];
    }
  }

  f32x4 accPV[8];
  #pragma unroll
  for (int nt = 0; nt < 8; ++nt) { f32x4 z = {0.f,0.f,0.f,0.f}; accPV[nt] = z; }
  float wsacc = 0.f;   // per-lane: sum over its 8 j-values for i = wv*16+lr

  const int giL = bi0 + wv * 16 + lr;
  const float sqi_l_init = sq[giL];

  // prologue: stage first tile (jt = slice < 8, never an attractor tile)
  LOADT(slice);
  STORET();
  __syncthreads();

  // ---- main loop: normal tiles only (jt < ATJT), straight-line mm4 PV ----
  int jt = slice;
  for (; jt < ATJT; jt += NSLICE) {
    const int jn = jt + NSLICE;
    const bool more = jn < NJTR;
    if (more) LOADT(jn);   // issue next tile's loads; latency hides under compute

    // S^T = rj . ri^T, 4-product split (lane holds i=lr, j=4lq+rr+16nt)
    f32x4 accST[2];
    { f32x4 z = {0.f,0.f,0.f,0.f}; accST[0] = z; accST[1] = z; }
    __builtin_amdgcn_s_setprio(1);
    #pragma unroll
    for (int kc = 0; kc < 4; ++kc) {
      int kq = kc * 4 + lq;
      #pragma unroll
      for (int nt = 0; nt < 2; ++nt) {
        int j = nt * 16 + lr;
        bf16x8 ah = *(const bf16x8*)&rjRM[0][j][kq * 8];
        bf16x8 am = *(const bf16x8*)&rjRM[1][j][kq * 8];
        accST[nt] = mm4(ah, am, riH[kc], riM[kc], accST[nt]);
      }
    }
    __builtin_amdgcn_s_setprio(0);

    // w phase: d2 -> w, 2-split into PV A-fragments (l-term not needed: mm4)
    bf16x8 aH, aM;
    #pragma unroll
    for (int nt = 0; nt < 2; ++nt)
      #pragma unroll
      for (int rr = 0; rr < 4; ++rr) {
        int jl = nt * 16 + 4 * lq + rr;
        int gj = jt * JTILE + jl;
        float d2 = fmaxf(sqi_l_init + sqj_s[jl] - 2.f * accST[nt][rr], 1e-6f);
        float rin = rsqrtf(d2);
        float wgt = mj_s[jl] * rin * rin * rin;
        if (giL == gj) wgt = 0.f;
        wsacc += wgt;
        __bf16 wh = (__bf16)wgt;
        __bf16 wm2 = (__bf16)(wgt - (float)wh);
        int e = nt * 4 + rr;   // slot e: j = 16*nt + 4*lq + rr  (matches jmap)
        aH[e] = wh; aM[e] = wm2;
      }

    // PV: A[i][d] += w @ rj, 4-product, straight-line
    __builtin_amdgcn_s_setprio(1);
    #pragma unroll
    for (int nt = 0; nt < 8; ++nt) {
      int d = nt * 16 + lr;
      bf16x8 bh = *(const bf16x8*)&rjT[0][d][lq * 8];
      bf16x8 bm = *(const bf16x8*)&rjT[1][d][lq * 8];
      accPV[nt] = mm4(aH, aM, bh, bm, accPV[nt]);
    }
    __builtin_amdgcn_s_setprio(0);

    __syncthreads();           // all waves done reading current tile's LDS
    if (more) STORET();        // write prefetched tile (waitcnt lands here)
    __syncthreads();           // next tile's LDS ready
  }

  // ---- peeled epilogue tile: the one attractor tile (slices 0/1), mm6 PV ----
  if (jt < NJTR) {
    f32x4 accST[2];
    { f32x4 z = {0.f,0.f,0.f,0.f}; accST[0] = z; accST[1] = z; }
    #pragma unroll
    for (int kc = 0; kc < 4; ++kc) {
      int kq = kc * 4 + lq;
      #pragma unroll
      for (int nt = 0; nt < 2; ++nt) {
        int j = nt * 16 + lr;
        bf16x8 ah = *(const bf16x8*)&rjRM[0][j][kq * 8];
        bf16x8 am = *(const bf16x8*)&rjRM[1][j][kq * 8];
        accST[nt] = mm4(ah, am, riH[kc], riM[kc], accST[nt]);
      }
    }

    bf16x8 aH, aM, aL;
    #pragma unroll
    for (int nt = 0; nt < 2; ++nt)
      #pragma unroll
      for (int rr = 0; rr < 4; ++rr) {
        int jl = nt * 16 + 4 * lq + rr;
        int gj = jt * JTILE + jl;
        float d2 = fmaxf(sqi_l_init + sqj_s[jl] - 2.f * accST[nt][rr], 1e-6f);
        float rin = rsqrtf(d2);
        float wgt = mj_s[jl] * rin * rin * rin;
        if (giL == gj) wgt = 0.f;
        wsacc += wgt;
        __bf16 wh, wm2, wl2; split3(wgt, wh, wm2, wl2);
        int e = nt * 4 + rr;
        aH[e] = wh; aM[e] = wm2; aL[e] = wl2;
      }

    #pragma unroll
    for (int nt = 0; nt < 8; ++nt) {
      int d = nt * 16 + lr;
      bf16x8 bh = *(const bf16x8*)&rjT[0][d][lq * 8];
      bf16x8 bm = *(const bf16x8*)&rjT[1][d][lq * 8];
      bf16x8 bl = *(const bf16x8*)&rjT[2][d][lq * 8];
      accPV[nt] = mm6(aH, aM, aL, bh, bm, bl, accPV[nt]);
    }
  }

  // ---- epilogue stores ----
  {
    float val = wsacc;
    val += __shfl_xor(val, 16);
    val += __shfl_xor(val, 32);
    int gi = bi0 + wv * 16 + lr;
    if (lane < 16 && gi < NROW) wsump[(size_t)slice * NROW + gi] = val;
  }
  #pragma unroll
  for (int nt = 0; nt < 8; ++nt)
    #pragma unroll
    for (int rr = 0; rr < 4; ++rr) {
      int gi = bi0 + wv * 16 + 4 * lq + rr;
      int d = nt * 16 + lr;
      if (gi < NROW) apart[((size_t)slice * NROW + gi) * DIM + d] = accPV[nt][rr];
    }
}

// ---------------- mlp: integrate + boundary + Hamiltonian + damp/clip + SPLIT EMIT ----------------
// r15: WR=8 (517 blocks, 2 blocks/CU co-resident -> 2x barrier-chain overlap).
// MFMA phases keep 16x16 shape; rows 8-15 are don't-care (MFMA output row i
// depends only on A row i -> stored rows bitwise identical to WR=16 version).
__global__ __launch_bounds__(256)
void k_mlp(float* __restrict__ r, float* __restrict__ v, float* __restrict__ sq,
           const float* __restrict__ apart, const float* __restrict__ wsump,
           const __bf16* __restrict__ wb1t, const __bf16* __restrict__ wb2t,
           const __bf16* __restrict__ wb3t,
           const __bf16* __restrict__ wp1t, const __bf16* __restrict__ wp1r,
           const __bf16* __restrict__ wk1t, const __bf16* __restrict__ wk1r,
           const float* __restrict__ bb1, const float* __restrict__ bb2,
           const float* __restrict__ bb3,
           const float* __restrict__ pb1, const float* __restrict__ pw2,
           const float* __restrict__ kb1, const float* __restrict__ kw2,
           __bf16* __restrict__ rh, __bf16* __restrict__ rm,
           __bf16* __restrict__ rth, __bf16* __restrict__ rtm,
           __bf16* __restrict__ rtl,
           int do_ham)
{
  __shared__ __align__(16) float  Cf[16][264];          // [r | v] f32 master (rows 8-15 don't-care)
  __shared__ __align__(16) __bf16 Csp[3][16][264];      // C 3-split
  __shared__ __align__(16) __bf16 Hsp[2][3][16][72];    // hidden 3-split, dbuf
  __shared__ __align__(16) __bf16 Gsp[3][16][264];      // ham (1-t^2)*w2 3-split

  const int tid = threadIdx.x;
  const int wv = tid >> 6, lane = tid & 63;
  const int lq = lane >> 4, lr = lane & 15;

  // ---------- phase A: reduce apart, integrate, stage C (8 rows x 32 thr/row) ----------
  {
    const int row = tid >> 5, c = tid & 31;       // row 0..7, col-group of 4
    const int grow = blockIdx.x * WR + row;       // always < NROW (517*8 = 4136)
    float s[4] = {0.f, 0.f, 0.f, 0.f};
    float wsv = 0.f;
    #pragma unroll
    for (int sl = 0; sl < NSLICE; ++sl) {
      float4 t0 = *(const float4*)&apart[((size_t)sl * NROW + grow) * DIM + c * 4];
      s[0] += t0.x; s[1] += t0.y; s[2] += t0.z; s[3] += t0.w;
      wsv += wsump[(size_t)sl * NROW + grow];
    }
    float4 ra = *(const float4*)&r[(size_t)grow * DIM + c * 4];
    float4 va = *(const float4*)&v[(size_t)grow * DIM + c * 4];
    float re[4] = {ra.x, ra.y, ra.z, ra.w};
    float ve[4] = {va.x, va.y, va.z, va.w};
    bf16x4 rh4, rm4, rl4, vh4, vm4, vl4;
    #pragma unroll
    for (int e = 0; e < 4; ++e) {
      float a = 1e-3f * (s[e] - wsv * re[e]);
      float vn = ve[e] + 0.1f * a;
      float rn = re[e] + 0.1f * vn;
      Cf[row][c * 4 + e] = rn;
      Cf[row][128 + c * 4 + e] = vn;
      __bf16 h, m, l;
      split3(rn, h, m, l); rh4[e] = h; rm4[e] = m; rl4[e] = l;
      split3(vn, h, m, l); vh4[e] = h; vm4[e] = m; vl4[e] = l;
    }
    *(bf16x4*)&Csp[0][row][c * 4] = rh4; *(bf16x4*)&Csp[0][row][128 + c * 4] = vh4;
    *(bf16x4*)&Csp[1][row][c * 4] = rm4; *(bf16x4*)&Csp[1][row][128 + c * 4] = vm4;
    *(bf16x4*)&Csp[2][row][c * 4] = rl4; *(bf16x4*)&Csp[2][row][128 + c * 4] = vl4;
  }
  __syncthreads();

  // ---------- L1: H1 = tanh(C @ bw1 + bb1) ----------
  {
    f32x4 acc = {0.f, 0.f, 0.f, 0.f};
    const __bf16* b = wb1t + ((size_t)(wv * 16 + lr)) * 256;
    #pragma unroll
    for (int kc = 0; kc < 8; ++kc) {
      int k0 = kc * 32 + lq * 8;
      bf16x8 ah = *(const bf16x8*)&Csp[0][lr][k0];
      bf16x8 am = *(const bf16x8*)&Csp[1][lr][k0];
      bf16x8 al = *(const bf16x8*)&Csp[2][lr][k0];
      bf16x8 b0 = *(const bf16x8*)&b[k0];
      bf16x8 b1 = *(const bf16x8*)&b[16384 + k0];
      bf16x8 b2 = *(const bf16x8*)&b[32768 + k0];
      acc = mm6(ah, am, al, b0, b1, b2, acc);
    }
    int n = wv * 16 + lr;
    float bias = bb1[n];
    #pragma unroll
    for (int reg = 0; reg < 4; ++reg) {
      int i = 4 * lq + reg;
      float h1 = tanhf(acc[reg] + bias);
      __bf16 h, m, l; split3(h1, h, m, l);
      Hsp[0][0][i][n] = h; Hsp[0][1][i][n] = m; Hsp[0][2][i][n] = l;
    }
  }
  __syncthreads();

  // ---------- L2: H2 = tanh(H1 @ bw2 + bb2) ----------
  {
    f32x4 acc = {0.f, 0.f, 0.f, 0.f};
    const __bf16* b = wb2t + ((size_t)(wv * 16 + lr)) * 64;
    #pragma unroll
    for (int kc = 0; kc < 2; ++kc) {
      int k0 = kc * 32 + lq * 8;
      bf16x8 ah = *(const bf16x8*)&Hsp[0][0][lr][k0];
      bf16x8 am = *(const bf16x8*)&Hsp[0][1][lr][k0];
      bf16x8 al = *(const bf16x8*)&Hsp[0][2][lr][k0];
      bf16x8 b0 = *(const bf16x8*)&b[k0];
      bf16x8 b1 = *(const bf16x8*)&b[4096 + k0];
      bf16x8 b2 = *(const bf16x8*)&b[8192 + k0];
      acc = mm6(ah, am, al, b0, b1, b2, acc);
    }
    int n = wv * 16 + lr;
    float bias = bb2[n];
    #pragma unroll
    for (int reg = 0; reg < 4; ++reg) {
      int i = 4 * lq + reg;
      float h2 = tanhf(acc[reg] + bias);
      __bf16 h, m, l; split3(h2, h, m, l);
      Hsp[1][0][i][n] = h; Hsp[1][1][i][n] = m; Hsp[1][2][i][n] = l;
    }
  }
  __syncthreads();

  // ---------- L3: r += 0.1*tanh(H2 @ bw3 + bb3) ----------
  {
    f32x4 acc[2];
    { f32x4 z = {0.f,0.f,0.f,0.f}; acc[0] = z; acc[1] = z; }
    #pragma unroll
    for (int kc = 0; kc < 2; ++kc) {
      int k0 = kc * 32 + lq * 8;
      bf16x8 ah = *(const bf16x8*)&Hsp[1][0][lr][k0];
      bf16x8 am = *(const bf16x8*)&Hsp[1][1][lr][k0];
      bf16x8 al = *(const bf16x8*)&Hsp[1][2][lr][k0];
      #pragma unroll
      for (int t = 0; t < 2; ++t) {
        const __bf16* b = wb3t + ((size_t)(t * 64 + wv * 16 + lr)) * 64;
        bf16x8 b0 = *(const bf16x8*)&b[k0];
        bf16x8 b1 = *(const bf16x8*)&b[8192 + k0];
        bf16x8 b2 = *(const bf16x8*)&b[16384 + k0];
        acc[t] = mm6(ah, am, al, b0, b1, b2, acc[t]);
      }
    }
    #pragma unroll
    for (int t = 0; t < 2; ++t) {
      int n = t * 64 + wv * 16 + lr;
      float bias = bb3[n];
      #pragma unroll
      for (int reg = 0; reg < 4; ++reg) {
        int i = 4 * lq + reg;
        float o = tanhf(acc[t][reg] + bias);
        float rn = Cf[i][n] + 0.1f * o;
        Cf[i][n] = rn;
        __bf16 h, m, l; split3(rn, h, m, l);
        Csp[0][i][n] = h; Csp[1][i][n] = m; Csp[2][i][n] = l;
      }
    }
  }
  __syncthreads();

  if (do_ham) {
    // ---- potential forward: G = (1-tanh^2(Cr@pw1+pb1))*pw2 ----
    {
      f32x4 acc[4];
      #pragma unroll
      for (int t = 0; t < 4; ++t) { f32x4 z = {0.f,0.f,0.f,0.f}; acc[t] = z; }
      #pragma unroll
      for (int kc = 0; kc < 4; ++kc) {
        int k0 = kc * 32 + lq * 8;
        bf16x8 ah = *(const bf16x8*)&Csp[0][lr][k0];
        bf16x8 am = *(const bf16x8*)&Csp[1][lr][k0];
        bf16x8 al = *(const bf16x8*)&Csp[2][lr][k0];
        #pragma unroll
        for (int t = 0; t < 4; ++t) {
          const __bf16* b = wp1t + ((size_t)(t * 64 + wv * 16 + lr)) * 128;
          bf16x8 b0 = *(const bf16x8*)&b[k0];
          bf16x8 b1 = *(const bf16x8*)&b[32768 + k0];
          bf16x8 b2 = *(const bf16x8*)&b[65536 + k0];
          acc[t] = mm6(ah, am, al, b0, b1, b2, acc[t]);
        }
      }
      #pragma unroll
      for (int t = 0; t < 4; ++t) {
        int n = t * 64 + wv * 16 + lr;
        float pb = pb1[n], pws = pw2[n];
        #pragma unroll
        for (int reg = 0; reg < 4; ++reg) {
          int i = 4 * lq + reg;
          float tt = tanhf(acc[t][reg] + pb);
          float g = (1.f - tt * tt) * pws;
          __bf16 h, m, l; split3(g, h, m, l);
          Gsp[0][i][n] = h; Gsp[1][i][n] = m; Gsp[2][i][n] = l;
        }
      }
    }
    __syncthreads();
    // ---- potential grad: r -= 0.01 * (G @ pw1 rows) ----
    {
      f32x4 acc[2];
      { f32x4 z = {0.f,0.f,0.f,0.f}; acc[0] = z; acc[1] = z; }
      #pragma unroll
      for (int kc = 0; kc < 8; ++kc) {
        int k0 = kc * 32 + lq * 8;
        bf16x8 ah = *(const bf16x8*)&Gsp[0][lr][k0];
        bf16x8 am = *(const bf16x8*)&Gsp[1][lr][k0];
        bf16x8 al = *(const bf16x8*)&Gsp[2][lr][k0];
        #pragma unroll
        for (int t = 0; t < 2; ++t) {
          const __bf16* b = wp1r + ((size_t)(t * 64 + wv * 16 + lr)) * 256;
          bf16x8 b0 = *(const bf16x8*)&b[k0];
          bf16x8 b1 = *(const bf16x8*)&b[32768 + k0];
          bf16x8 b2 = *(const bf16x8*)&b[65536 + k0];
          acc[t] = mm6(ah, am, al, b0, b1, b2, acc[t]);
        }
      }
      #pragma unroll
      for (int t = 0; t < 2; ++t)
        #pragma unroll
        for (int reg = 0; reg < 4; ++reg) {
          int i = 4 * lq + reg, d = t * 64 + wv * 16 + lr;
          float rn = Cf[i][d] - 0.01f * acc[t][reg];
          Cf[i][d] = rn;
          __bf16 h, m, l; split3(rn, h, m, l);
          Csp[0][i][d] = h; Csp[1][i][d] = m; Csp[2][i][d] = l;
        }
    }
    __syncthreads();
    // ---- kinetic forward on v ----
    {
      f32x4 acc[4];
      #pragma unroll
      for (int t = 0; t < 4; ++t) { f32x4 z = {0.f,0.f,0.f,0.f}; acc[t] = z; }
      #pragma unroll
      for (int kc = 0; kc < 4; ++kc) {
        int k0 = 128 + kc * 32 + lq * 8;
        bf16x8 ah = *(const bf16x8*)&Csp[0][lr][k0];
        bf16x8 am = *(const bf16x8*)&Csp[1][lr][k0];
        bf16x8 al = *(const bf16x8*)&Csp[2][lr][k0];
        #pragma unroll
        for (int t = 0; t < 4; ++t) {
          const __bf16* b = wk1t + ((size_t)(t * 64 + wv * 16 + lr)) * 128;
          int kb = kc * 32 + lq * 8;
          bf16x8 b0 = *(const bf16x8*)&b[kb];
          bf16x8 b1 = *(const bf16x8*)&b[32768 + kb];
          bf16x8 b2 = *(const bf16x8*)&b[65536 + kb];
          acc[t] = mm6(ah, am, al, b0, b1, b2, acc[t]);
        }
      }
      #pragma unroll
      for (int t = 0; t < 4; ++t) {
        int n = t * 64 + wv * 16 + lr;
        float kb = kb1[n], kws = kw2[n];
        #pragma unroll
        for (int reg = 0; reg < 4; ++reg) {
          int i = 4 * lq + reg;
          float tt = tanhf(acc[t][reg] + kb);
          float g = (1.f - tt * tt) * kws;
          __bf16 h, m, l; split3(g, h, m, l);
          Gsp[0][i][n] = h; Gsp[1][i][n] = m; Gsp[2][i][n] = l;
        }
      }
    }
    __syncthreads();
    // ---- kinetic grad: v += 0.01 * (G @ kw1 rows) ----
    {
      f32x4 acc[2];
      { f32x4 z = {0.f,0.f,0.f,0.f}; acc[0] = z; acc[1] = z; }
      #pragma unroll
      for (int kc = 0; kc < 8; ++kc) {
        int k0 = kc * 32 + lq * 8;
        bf16x8 ah = *(const bf16x8*)&Gsp[0][lr][k0];
        bf16x8 am = *(const bf16x8*)&Gsp[1][lr][k0];
        bf16x8 al = *(const bf16x8*)&Gsp[2][lr][k0];
        #pragma unroll
        for (int t = 0; t < 2; ++t) {
          const __bf16* b = wk1r + ((size_t)(t * 64 + wv * 16 + lr)) * 256;
          bf16x8 b0 = *(const bf16x8*)&b[k0];
          bf16x8 b1 = *(const bf16x8*)&b[32768 + k0];
          bf16x8 b2 = *(const bf16x8*)&b[65536 + k0];
          acc[t] = mm6(ah, am, al, b0, b1, b2, acc[t]);
        }
      }
      #pragma unroll
      for (int t = 0; t < 2; ++t)
        #pragma unroll
        for (int reg = 0; reg < 4; ++reg) {
          int i = 4 * lq + reg, d = t * 64 + wv * 16 + lr;
          Cf[i][128 + d] += 0.01f * acc[t][reg];
        }
    }
    __syncthreads();
  }

  // ---------- phase F: damp, clip, writeback + fused split (8 rows x 32 thr/row) ----------
  {
    const int row = tid >> 5, c = tid & 31;
    const int grow = blockIdx.x * WR + row;       // always < NROW
    float re[4], ve[4];
    #pragma unroll
    for (int e = 0; e < 4; ++e) {
      re[e] = Cf[row][c * 4 + e];
      ve[e] = Cf[row][128 + c * 4 + e] * 0.95f;
    }
    float n2 = 0.f;
    #pragma unroll
    for (int e = 0; e < 4; ++e) n2 += re[e] * re[e];
    n2 += __shfl_xor(n2, 1); n2 += __shfl_xor(n2, 2);
    n2 += __shfl_xor(n2, 4); n2 += __shfl_xor(n2, 8);
    n2 += __shfl_xor(n2, 16);
    float nrm = sqrtf(n2);
    float sc = fminf(1.f, 10.f / fmaxf(nrm, 1e-12f));
    float rs[4];
    #pragma unroll
    for (int e = 0; e < 4; ++e) rs[e] = re[e] * sc;
    bf16x4 h4, m4, l4;
    #pragma unroll
    for (int e = 0; e < 4; ++e) {
      __bf16 h, m, l; split3(rs[e], h, m, l);
      h4[e] = h; m4[e] = m; l4[e] = l;
    }
    // stage splits for transpose emit
    *(bf16x4*)&Csp[0][row][c * 4] = h4;
    *(bf16x4*)&Csp[1][row][c * 4] = m4;
    *(bf16x4*)&Csp[2][row][c * 4] = l4;
    {
      float4 o0, w0;
      o0.x = rs[0]; o0.y = rs[1]; o0.z = rs[2]; o0.w = rs[3];
      w0.x = ve[0]; w0.y = ve[1]; w0.z = ve[2]; w0.w = ve[3];
      *(float4*)&r[(size_t)grow * DIM + c * 4] = o0;
      *(float4*)&v[(size_t)grow * DIM + c * 4] = w0;
      *(bf16x4*)&rh[(size_t)grow * DIM + c * 4] = h4;
      *(bf16x4*)&rm[(size_t)grow * DIM + c * 4] = m4;
      if (c == 0) sq[grow] = n2 * sc * sc;
    }
  }
  __syncthreads();
  // ---------- transposed j-permuted split emit (this block's 8 j's) ----------
  // Block covers j = blockIdx*8 .. +8 within 32-block b32 = blockIdx>>2,
  // quarter q = blockIdx&3. Slot of local row (4a'+c): s = ((q&1)*2+a')*8 + (q>>1)*4 + c.
  {
    const int q = blockIdx.x & 3;
    const int b32 = blockIdx.x >> 2;
    const int Abase = (q & 1) * 2;
    const int hoff = (q >> 1) * 4;
    for (int u = tid; u < 384; u += 256) {
      int s = u >> 7, d = u & 127;
      __bf16* dst = (s == 0 ? rth : (s == 1 ? rtm : rtl))
                    + (size_t)d * MP + b32 * 32;
      #pragma unroll
      for (int ap2 = 0; ap2 < 2; ++ap2) {
        bf16x4 qv;
        #pragma unroll
        for (int c2 = 0; c2 < 4; ++c2) qv[c2] = Csp[s][4 * ap2 + c2][d];
        *(bf16x4*)&dst[(Abase + ap2) * 8 + hoff] = qv;
      }
    }
  }
}

// ---------------- feature kernels ----------------
__global__ void k_statinit(double* pd_sum, double* pd_sumsq,
                           unsigned* pd_min, unsigned* pd_max)
{
  if (threadIdx.x == 0) {
    *pd_sum = 0.0; *pd_sumsq = 0.0;
    *pd_min = 0x7f7fffffu;
    *pd_max = 0u;
  }
}

__global__ __launch_bounds__(256)
void k_com(const float* __restrict__ r, const float* __restrict__ am,
           float* __restrict__ feat)
{
  int b = blockIdx.x, ch = blockIdx.y;
  int c = threadIdx.x & 31, rg = threadIdx.x >> 5;
  int col = ch * 32 + c;
  __shared__ float red[8][33];
  float amsum = 0.f;
  for (int k = 0; k < 10; ++k) amsum += am[k];
  float tot = 1024.f + amsum;

  float s = 0.f;
  #pragma unroll 4
  for (int p = rg; p < NPTS; p += 8) {
    int row = p < 1024 ? b * 1024 + p : NPART + b * 10 + (p - 1024);
    float m = p < 1024 ? 1.f : am[p - 1024];
    s += m * r[(size_t)row * DIM + col];
  }
  red[rg][c] = s; __syncthreads();
  for (int h = 4; h >= 1; h >>= 1) { if (rg < h) red[rg][c] += red[rg + h][c]; __syncthreads(); }
  float com = red[0][c] / tot;
  __syncthreads();

  float s2 = 0.f, s3 = 0.f;
  #pragma unroll 4
  for (int p = rg; p < NPTS; p += 8) {
    int row = p < 1024 ? b * 1024 + p : NPART + b * 10 + (p - 1024);
    float cc = r[(size_t)row * DIM + col] - com;
    s2 += cc * cc; s3 += cc * cc * cc;
  }
  red[rg][c] = s2; __syncthreads();
  for (int h = 4; h >= 1; h >>= 1) { if (rg < h) red[rg][c] += red[rg + h][c]; __syncthreads(); }
  float var = red[0][c] / 1034.f;
  __syncthreads();
  red[rg][c] = s3; __syncthreads();
  for (int h = 4; h >= 1; h >>= 1) { if (rg < h) red[rg][c] += red[rg + h][c]; __syncthreads(); }
  float skw = red[0][c] / 1034.f;
  if (rg == 0) {
    feat[b * 384 + col]       = com;
    feat[b * 384 + 128 + col] = var;
    feat[b * 384 + 256 + col] = skw;
  }
}

__global__ __launch_bounds__(256)
void k_pdist(const float* __restrict__ r, const float* __restrict__ sq,
             double* pd_sum, double* pd_sumsq, unsigned* pd_min, unsigned* pd_max)
{
  int ta = blockIdx.x, tb = blockIdx.y;
  if (ta > tb) return;
  __shared__ __align__(16) float pa_s[64 * DIM];
  __shared__ __align__(16) float pb_s[64 * DIM];
  __shared__ float sqa_s[64], sqb_s[64];
  const int tid = threadIdx.x;
  const int tx = tid & 15, ty = tid >> 4;

  #pragma unroll
  for (int p = 0; p < 8; ++p) {
    int q = tid + p * 256;
    int row = q >> 5, slot = q & 31;
    int pidx = ta * 64 + row;
    float4 val = make_float4(0.f, 0.f, 0.f, 0.f);
    if (pidx < NPTS) {
      int srow = pidx < 1024 ? pidx : (NPART + pidx - 1024);
      val = *(const float4*)&r[(size_t)srow * DIM + slot * 4];
    }
    *(float4*)&pa_s[lds_off(row, slot)] = val;
    pidx = tb * 64 + row;
    val = make_float4(0.f, 0.f, 0.f, 0.f);
    if (pidx < NPTS) {
      int srow = pidx < 1024 ? pidx : (NPART + pidx - 1024);
      val = *(const float4*)&r[(size_t)srow * DIM + slot * 4];
    }
    *(float4*)&pb_s[lds_off(row, slot)] = val;
  }
  if (tid < 64) {
    int pidx = ta * 64 + tid;
    sqa_s[tid] = pidx < NPTS ? sq[pidx < 1024 ? pidx : NPART + pidx - 1024] : 0.f;
  } else if (tid < 128) {
    int t2 = tid - 64;
    int pidx = tb * 64 + t2;
    sqb_s[t2] = pidx < NPTS ? sq[pidx < 1024 ? pidx : NPART + pidx - 1024] : 0.f;
  }
  __syncthreads();

  const int swi = ty & 7, swj = tx & 7;
  float sv[4][4] = {};
  #pragma unroll 8
  for (int ks = 0; ks < 32; ++ks) {
    int oi = (ks ^ swi) << 2, oj = (ks ^ swj) << 2;
    float4 av[4], bv[4];
    #pragma unroll
    for (int a = 0; a < 4; ++a) av[a] = *(const float4*)&pa_s[(ty * 4 + a) * DIM + oi];
    #pragma unroll
    for (int b = 0; b < 4; ++b) bv[b] = *(const float4*)&pb_s[(tx * 4 + b) * DIM + oj];
    #pragma unroll
    for (int a = 0; a < 4; ++a)
      #pragma unroll
      for (int b = 0; b < 4; ++b) sv[a][b] = dot4acc(sv[a][b], av[a], bv[b]);
  }

  double tsum = 0.0, tsq = 0.0;
  float tmn = 3.402823466e38f, tmx = 0.f;
  #pragma unroll
  for (int a = 0; a < 4; ++a)
    #pragma unroll
    for (int b = 0; b < 4; ++b) {
      int ga = ta * 64 + ty * 4 + a;
      int gb = tb * 64 + tx * 4 + b;
      float d2 = sqa_s[ty * 4 + a] + sqb_s[tx * 4 + b] - 2.f * sv[a][b];
      float dist = sqrtf(fmaxf(d2, 0.f));
      bool ok = (ga < NPTS) && (gb < NPTS) && ((ta != tb) || (ga < gb));
      if (ok) {
        tsum += (double)dist;
        tsq  += (double)dist * (double)dist;
        tmn = fminf(tmn, dist);
        tmx = fmaxf(tmx, dist);
      }
    }
  for (int mk = 1; mk < 64; mk <<= 1) {
    tsum += __shfl_xor(tsum, mk);
    tsq  += __shfl_xor(tsq, mk);
    tmn = fminf(tmn, __shfl_xor(tmn, mk));
    tmx = fmaxf(tmx, __shfl_xor(tmx, mk));
  }
  if ((tid & 63) == 0) {
    atomicAdd(pd_sum, tsum);
    atomicAdd(pd_sumsq, tsq);
    atomicMin(pd_min, __float_as_uint(tmn));
    atomicMax(pd_max, __float_as_uint(tmx));
  }
}

__global__ void k_proj(const float* __restrict__ feat,
                       const double* pd_sum, const double* pd_sumsq,
                       const unsigned* pd_min, const unsigned* pd_max,
                       const float* __restrict__ fw, const float* __restrict__ fb,
                       float* __restrict__ out)
{
  int t = threadIdx.x;
  int b = t >> 7, d = t & 127;
  double sm = *pd_sum, s2 = *pd_sumsq;
  double mean = sm / NPAIRS;
  double var = (s2 - sm * sm / NPAIRS) / (NPAIRS - 1.0);
  float sd = (float)sqrt(var > 0.0 ? var : 0.0);
  float mn = __uint_as_float(*pd_min);
  float mx = __uint_as_float(*pd_max);
  float acc0 = fb[d], acc1 = 0.f, acc2 = 0.f, acc3 = 0.f;
  #pragma unroll 8
  for (int f = 0; f < 384; f += 4) {
    acc0 = fmaf(feat[b * 384 + f + 0], fw[(f + 0) * 128 + d], acc0);
    acc1 = fmaf(feat[b * 384 + f + 1], fw[(f + 1) * 128 + d], acc1);
    acc2 = fmaf(feat[b * 384 + f + 2], fw[(f + 2) * 128 + d], acc2);
    acc3 = fmaf(feat[b * 384 + f + 3], fw[(f + 3) * 128 + d], acc3);
  }
  float acc = (acc0 + acc1) + (acc2 + acc3);
  acc = fmaf((float)mean, fw[384 * 128 + d], acc);
  acc = fmaf(sd,          fw[385 * 128 + d], acc);
  acc = fmaf(mn,          fw[386 * 128 + d], acc);
  acc = fmaf(mx,          fw[387 * 128 + d], acc);
  out[b * 128 + d] = acc;
}

extern "C" void kernel_launch(void* const* d_in, const int* in_sizes, int n_in,
                              void* d_out, int out_size, void* d_ws, size_t ws_size,
                              hipStream_t stream) {
  (void)in_sizes; (void)n_in; (void)out_size; (void)ws_size;
  const float* x   = (const float*)d_in[0];
  const float* ap  = (const float*)d_in[1];
  const float* am  = (const float*)d_in[2];
  const float* v0  = (const float*)d_in[3];
  const float* pw1 = (const float*)d_in[4];
  const float* pb1 = (const float*)d_in[5];
  const float* pw2 = (const float*)d_in[6];
  const float* kw1 = (const float*)d_in[8];
  const float* kb1 = (const float*)d_in[9];
  const float* kw2 = (const float*)d_in[10];
  const float* bw1 = (const float*)d_in[12];
  const float* bb1 = (const float*)d_in[13];
  const float* bw2 = (const float*)d_in[14];
  const float* bb2 = (const float*)d_in[15];
  const float* bw3 = (const float*)d_in[16];
  const float* bb3 = (const float*)d_in[17];
  const float* fw  = (const float*)d_in[18];
  const float* fb  = (const float*)d_in[19];

  // workspace layout (bytes), 16B-aligned; same extents as rounds 5-14
  char* ws = (char*)d_ws;
  double*   pd_sum   = (double*)(ws + 0);
  double*   pd_sumsq = (double*)(ws + 8);
  unsigned* pd_min   = (unsigned*)(ws + 16);
  unsigned* pd_max   = (unsigned*)(ws + 20);
  float*    feat     = (float*)(ws + 32);        // 4*384 f32
  float*    r        = (float*)(ws + 6176);      // MP*128 f32
  float*    v        = (float*)(ws + 2168864);   // MP*128 f32
  float*    sq       = (float*)(ws + 4331552);   // MP f32
  float*    wsump    = (float*)(ws + 4348448);   // NSLICE*NROW f32
  float*    apart    = (float*)(ws + 4480800);   // NSLICE*NROW*128 f32
  __bf16*   rh       = (__bf16*)(ws + 21421856); // MP*128 bf16
  __bf16*   rm       = (__bf16*)(ws + 22503200);
  // (ws + 23584544: former rl slot, unused)
  __bf16*   rth      = (__bf16*)(ws + 24665888); // 128*MP bf16 (transposed, j-permuted)
  __bf16*   rtm      = (__bf16*)(ws + 25747232);
  __bf16*   rtl      = (__bf16*)(ws + 26828576); // ends 27909920
  // pre-split weights (h|m|l planes packed per array)
  __bf16*   wb1t     = (__bf16*)(ws + 27909920); // 3*16384
  __bf16*   wb2t     = (__bf16*)(ws + 28008224); // 3*4096
  __bf16*   wb3t     = (__bf16*)(ws + 28032800); // 3*8192
  __bf16*   wp1t     = (__bf16*)(ws + 28081952); // 3*32768
  __bf16*   wp1r     = (__bf16*)(ws + 28278560); // 3*32768
  __bf16*   wk1t     = (__bf16*)(ws + 28475168); // 3*32768
  __bf16*   wk1r     = (__bf16*)(ws + 28671776); // 3*32768 -> ends 28868384

  k_wprep<<<dim3(128, 7), 256, 0, stream>>>(bw1, bw2, bw3, pw1, kw1,
                                            wb1t, wb2t, wb3t, wp1t, wp1r, wk1t, wk1r);
  k_init<<<MP / 4, 256, 0, stream>>>(x, ap, am, v0, r, v, sq);
  // one-time full split (covers all 4224 rows; pads become zeros and stay zero)
  k_split<<<MP / 32, 256, 0, stream>>>(r, rh, rm, rth, rtm, rtl);
  for (int it = 0; it < NITER; ++it) {
    // grid (slice, itile): flat_wg % 8 == slice -> per-slice j-stream is XCD-local
    k_force<<<dim3(NSLICE, NIBR), 256, 0, stream>>>(rh, rm, rth, rtm, rtl,
                                                    sq, am, apart, wsump);
    k_mlp<<<NMLPB, 256, 0, stream>>>(r, v, sq, apart, wsump,
        wb1t, wb2t, wb3t, wp1t, wp1r, wk1t, wk1r,
        bb1, bb2, bb3, pb1, pw2, kb1, kw2,
        rh, rm, rth, rtm, rtl,
        (it % 5) == 0 ? 1 : 0);
  }
  k_statinit<<<1, 64, 0, stream>>>(pd_sum, pd_sumsq, pd_min, pd_max);
  k_com<<<dim3(4, 4), 256, 0, stream>>>(r, am, feat);
  k_pdist<<<dim3(17, 17), 256, 0, stream>>>(r, sq, pd_sum, pd_sumsq, pd_min, pd_max);
  k_proj<<<1, 512, 0, stream>>>(feat, pd_sum, pd_sumsq, pd_min, pd_max, fw, fb,
                                (float*)d_out);
}

// Round 16
// 4568.797 us; speedup vs baseline: 1.1553x; 1.1553x over previous
//
#include <hip/hip_runtime.h>
#include <hip/hip_bf16.h>
#include <math.h>

// ---- static problem config ----
#define DIM    128
#define NPART  4096      // B*N particles
#define MREAL  4136      // NPART + B*K
#define MP     4224      // padded; pad rows mass 0, r=0 (splits zeroed once)
#define IB     64        // i-rows per force block
#define NIBR   65        // i-tiles covering real rows
#define JTILE  32        // j-tile
#define NJTR   130       // j-tiles covering real rows
#define ATJT   128       // first j-tile containing attractor rows (>=4096)
#define NSLICE 8
#define NROW   4136      // rows stored in apart/wsump (real rows only)
#define NITER  50
#define NPTS   1034
#define NPAIRS 534061.0
#define WR     16        // rows per k_mlp block (r14 anchor config)
#define NMLPB  259       // ceil(NROW/WR)

typedef __bf16 bf16x8 __attribute__((ext_vector_type(8)));
typedef __bf16 bf16x4 __attribute__((ext_vector_type(4)));
typedef float  f32x4  __attribute__((ext_vector_type(4)));

__device__ __forceinline__ f32x4 mfma16(bf16x8 a, bf16x8 b, f32x4 c) {
  return __builtin_amdgcn_mfma_f32_16x16x32_bf16(a, b, c, 0, 0, 0);
}
__device__ __forceinline__ float dot4acc(float s, float4 a, float4 b) {
  s = fmaf(a.x, b.x, s); s = fmaf(a.y, b.y, s);
  s = fmaf(a.z, b.z, s); s = fmaf(a.w, b.w, s);
  return s;
}
__device__ __forceinline__ void split3(float x, __bf16& h, __bf16& m, __bf16& l) {
  h = (__bf16)x; float t = x - (float)h;
  m = (__bf16)t; l = (__bf16)(t - (float)m);
}
// 6-product split accumulate: f32-faithful C += A*B
__device__ __forceinline__ f32x4 mm6(bf16x8 ah, bf16x8 am, bf16x8 al,
                                     bf16x8 bh, bf16x8 bm, bf16x8 bl, f32x4 c) {
  c = mfma16(ah, bh, c);
  c = mfma16(ah, bm, c);
  c = mfma16(am, bh, c);
  c = mfma16(am, bm, c);
  c = mfma16(ah, bl, c);
  c = mfma16(al, bh, c);
  return c;
}
// 4-product split accumulate: (h+m)*(h+m), rel ~2^-17
__device__ __forceinline__ f32x4 mm4(bf16x8 ah, bf16x8 am,
                                     bf16x8 bh, bf16x8 bm, f32x4 c) {
  c = mfma16(ah, bh, c);
  c = mfma16(ah, bm, c);
  c = mfma16(am, bh, c);
  c = mfma16(am, bm, c);
  return c;
}
// LDS swizzle for k_pdist (unchanged)
__device__ __forceinline__ int lds_off(int row, int slot) {
  return row * DIM + ((slot ^ ((row >> 2) & 7)) << 2);
}
// j-slot permutation baked into rjT: slot s holds j = 4*(s>>3)+(s&3)+16*((s>>2)&1)
__device__ __forceinline__ int jmap(int s) {
  return 4 * (s >> 3) + (s & 3) + 16 * ((s >> 2) & 1);
}

// ---------------- init: build padded state + sq ----------------
__global__ __launch_bounds__(256)
void k_init(const float* __restrict__ x, const float* __restrict__ ap,
            const float* __restrict__ am, const float* __restrict__ v0in,
            float* __restrict__ r, float* __restrict__ v, float* __restrict__ sq)
{
  int wid = threadIdx.x >> 6, ln = threadIdx.x & 63;
  int row = blockIdx.x * 4 + wid;
  int d0 = ln, d1 = ln + 64;
  size_t base = (size_t)row * DIM;
  float r0, r1, w0, w1;
  if (row < NPART) {
    r0 = x[base + d0]; r1 = x[base + d1]; w0 = 0.f; w1 = 0.f;
  } else if (row < MREAL) {
    int k = (row - NPART) % 10;
    r0 = ap[k * DIM + d0]; r1 = ap[k * DIM + d1];
    w0 = v0in[k * DIM + d0]; w1 = v0in[k * DIM + d1];
  } else {
    r0 = r1 = w0 = w1 = 0.f;
  }
  r[base + d0] = r0; r[base + d1] = r1;
  v[base + d0] = w0; v[base + d1] = w1;
  float n2 = r0 * r0 + r1 * r1;
  for (int mk = 1; mk < 64; mk <<= 1) n2 += __shfl_xor(n2, mk);
  if (ln == 0) { sq[row] = n2; }
}

// ---------------- wprep: split(+transpose) constant weights, ONCE ----------------
__global__ __launch_bounds__(256)
void k_wprep(const float* __restrict__ bw1, const float* __restrict__ bw2,
             const float* __restrict__ bw3, const float* __restrict__ pw1,
             const float* __restrict__ kw1,
             __bf16* __restrict__ wb1t, __bf16* __restrict__ wb2t,
             __bf16* __restrict__ wb3t, __bf16* __restrict__ wp1t,
             __bf16* __restrict__ wp1r, __bf16* __restrict__ wk1t,
             __bf16* __restrict__ wk1r)
{
  int a = blockIdx.y;
  int e = blockIdx.x * 256 + threadIdx.x;
  float val; __bf16* dst; int size;
  if (a == 0)      { size = 16384; if (e >= size) return; int n = e >> 8, k = e & 255; val = bw1[k * 64 + n];  dst = wb1t; }
  else if (a == 1) { size = 4096;  if (e >= size) return; int n = e >> 6, k = e & 63;  val = bw2[k * 64 + n];  dst = wb2t; }
  else if (a == 2) { size = 8192;  if (e >= size) return; int n = e >> 6, k = e & 63;  val = bw3[k * 128 + n]; dst = wb3t; }
  else if (a == 3) { size = 32768; if (e >= size) return; int n = e >> 7, d = e & 127; val = pw1[d * 256 + n]; dst = wp1t; }
  else if (a == 4) { size = 32768; if (e >= size) return; val = pw1[e]; dst = wp1r; }
  else if (a == 5) { size = 32768; if (e >= size) return; int n = e >> 7, d = e & 127; val = kw1[d * 256 + n]; dst = wk1t; }
  else             { size = 32768; if (e >= size) return; val = kw1[e]; dst = wk1r; }
  __bf16 h, m, l; split3(val, h, m, l);
  dst[e] = h; dst[size + e] = m; dst[2 * size + e] = l;
}

// ---------------- split: ONE-TIME full split of initial state (incl. pads) ----------------
__global__ __launch_bounds__(256)
void k_split(const float* __restrict__ r,
             __bf16* __restrict__ rh, __bf16* __restrict__ rm,
             __bf16* __restrict__ rth, __bf16* __restrict__ rtm, __bf16* __restrict__ rtl)
{
  __shared__ __bf16 hs[32][132], ms2[32][132], ls[32][132];
  const int tid = threadIdx.x;
  const int row = tid >> 3, cg = tid & 7;    // row 0..31, col-group of 16
  const int grow = blockIdx.x * 32 + row;
  const float* rp = &r[(size_t)grow * DIM + cg * 16];
  float4 f0 = *(const float4*)&rp[0];
  float4 f1 = *(const float4*)&rp[4];
  float4 f2 = *(const float4*)&rp[8];
  float4 f3 = *(const float4*)&rp[12];
  float xs[16] = {f0.x,f0.y,f0.z,f0.w, f1.x,f1.y,f1.z,f1.w,
                  f2.x,f2.y,f2.z,f2.w, f3.x,f3.y,f3.z,f3.w};
  bf16x8 hq[2], mq[2];
  #pragma unroll
  for (int e = 0; e < 16; ++e) {
    float xv = xs[e];
    __bf16 hh, mm, ll; split3(xv, hh, mm, ll);
    hq[e >> 3][e & 7] = hh; mq[e >> 3][e & 7] = mm;
    hs[row][cg * 16 + e] = hh; ms2[row][cg * 16 + e] = mm; ls[row][cg * 16 + e] = ll;
  }
  size_t ob = (size_t)grow * DIM + cg * 16;
  *(bf16x8*)&rh[ob] = hq[0]; *(bf16x8*)&rh[ob + 8] = hq[1];
  *(bf16x8*)&rm[ob] = mq[0]; *(bf16x8*)&rm[ob + 8] = mq[1];
  __syncthreads();
  for (int u = tid; u < 384; u += 256) {
    int s = u >> 7, d = u & 127;
    const __bf16* src = s == 0 ? &hs[0][0] : (s == 1 ? &ms2[0][0] : &ls[0][0]);
    __bf16 col[32];
    #pragma unroll
    for (int j = 0; j < 32; ++j) col[j] = src[j * 132 + d];
    __bf16* dst = (s == 0 ? rth : (s == 1 ? rtm : rtl)) + (size_t)d * MP + blockIdx.x * 32;
    #pragma unroll
    for (int c = 0; c < 4; ++c) {
      bf16x8 q;
      #pragma unroll
      for (int e = 0; e < 8; ++e) q[e] = col[jmap(c * 8 + e)];
      *(bf16x8*)&dst[c * 8] = q;
    }
  }
}

// ---------------- force: split-bf16 MFMA all-pairs gravity ----------------
// r14 anchor: ZERO branches in the hot loop. Main loop covers jt < ATJT with a
// straight-line mm4 PV; the single attractor tile per block (slices 0/1 only,
// always the LAST staged tile) is PEELED into a straight-line mm6 epilogue.
__global__ __launch_bounds__(256, 3)
void k_force(const __bf16* __restrict__ rh, const __bf16* __restrict__ rm,
             const __bf16* __restrict__ rth, const __bf16* __restrict__ rtm,
             const __bf16* __restrict__ rtl,
             const float* __restrict__ sq, const float* __restrict__ am,
             float* __restrict__ apart, float* __restrict__ wsump)
{
  __shared__ __align__(16) __bf16 rjRM[2][JTILE][136];  // h,m row-major (S A-operand)
  __shared__ __align__(16) __bf16 rjT[3][DIM][40];      // h,m,l transposed, j-permuted
  __shared__ float sqi_s[IB], sqj_s[JTILE], mj_s[JTILE];

  const int tid = threadIdx.x;
  const int wv = tid >> 6, lane = tid & 63;
  const int lq = lane >> 4, lr = lane & 15;
  const int slice = blockIdx.x;            // XCD = flat%8 = slice
  const int bi0 = blockIdx.y * IB;

  if (tid < IB) sqi_s[tid] = sq[bi0 + tid];

  // staging decode (fixed per thread)
  const int u1 = tid + 256;
  const int sr0 = tid >> 4, sc0 = tid & 15;     // rjRM half 0
  const int sr1 = u1 >> 4,  sc1 = u1 & 15;      // rjRM half 1
  const int td0 = tid >> 2, te0 = tid & 3;      // rjT half 0 (d 0..63)
  const int td1 = u1 >> 2,  te1 = u1 & 3;       // rjT half 1 (d 64..127)

  bf16x8 pr[10];
  float psqj = 0.f, pmj = 0.f;

  auto LOADT = [&](int jt) {
    size_t ga0 = (size_t)(jt * JTILE + sr0) * DIM + sc0 * 8;
    size_t ga1 = (size_t)(jt * JTILE + sr1) * DIM + sc1 * 8;
    pr[0] = *(const bf16x8*)&rh[ga0];  pr[1] = *(const bf16x8*)&rm[ga0];
    pr[2] = *(const bf16x8*)&rh[ga1];  pr[3] = *(const bf16x8*)&rm[ga1];
    size_t gb0 = (size_t)td0 * MP + jt * JTILE + te0 * 8;
    size_t gb1 = (size_t)td1 * MP + jt * JTILE + te1 * 8;
    pr[4] = *(const bf16x8*)&rth[gb0]; pr[5] = *(const bf16x8*)&rtm[gb0];
    pr[6] = *(const bf16x8*)&rtl[gb0]; pr[7] = *(const bf16x8*)&rth[gb1];
    pr[8] = *(const bf16x8*)&rtm[gb1]; pr[9] = *(const bf16x8*)&rtl[gb1];
    if (tid < JTILE) {
      int gj = jt * JTILE + tid;
      psqj = sq[gj];
      pmj = gj < NPART ? 0.1f : (gj < MREAL ? am[(gj - NPART) % 10] : 0.f);
    }
  };
  auto STORET = [&]() {
    *(bf16x8*)&rjRM[0][sr0][sc0 * 8] = pr[0];
    *(bf16x8*)&rjRM[1][sr0][sc0 * 8] = pr[1];
    *(bf16x8*)&rjRM[0][sr1][sc1 * 8] = pr[2];
    *(bf16x8*)&rjRM[1][sr1][sc1 * 8] = pr[3];
    *(bf16x8*)&rjT[0][td0][te0 * 8] = pr[4];
    *(bf16x8*)&rjT[1][td0][te0 * 8] = pr[5];
    *(bf16x8*)&rjT[2][td0][te0 * 8] = pr[6];
    *(bf16x8*)&rjT[0][td1][te1 * 8] = pr[7];
    *(bf16x8*)&rjT[1][td1][te1 * 8] = pr[8];
    *(bf16x8*)&rjT[2][td1][te1 * 8] = pr[9];
    if (tid < JTILE) { sqj_s[tid] = psqj; mj_s[tid] = pmj; }
  };

  // i-fragments (16 rows per wave), h,m splits (S is 4-product)
  bf16x8 riH[4], riM[4];
  {
    int gi = bi0 + wv * 16 + lr;
    const __bf16* ph = &rh[(size_t)gi * DIM];
    const __bf16* pm = &rm[(size_t)gi * DIM];
    #pragma unroll
    for (int kc = 0; kc < 4; ++kc) {
      riH[kc] = *(const bf16x8*)&ph[kc * 32 + lq * 8];
      riM[kc] = *(const bf16x8*)&pm[kc * 32 + lq * 8];
    }
  }

  f32x4 accPV[8];
  #pragma unroll
  for (int nt = 0; nt < 8; ++nt) { f32x4 z = {0.f,0.f,0.f,0.f}; accPV[nt] = z; }
  float wsacc = 0.f;   // per-lane: sum over its 8 j-values for i = wv*16+lr

  const int giL = bi0 + wv * 16 + lr;
  const float sqi_l_init = sq[giL];

  // prologue: stage first tile (jt = slice < 8, never an attractor tile)
  LOADT(slice);
  STORET();
  __syncthreads();

  // ---- main loop: normal tiles only (jt < ATJT), straight-line mm4 PV ----
  int jt = slice;
  for (; jt < ATJT; jt += NSLICE) {
    const int jn = jt + NSLICE;
    const bool more = jn < NJTR;
    if (more) LOADT(jn);   // issue next tile's loads; latency hides under compute

    // S^T = rj . ri^T, 4-product split (lane holds i=lr, j=4lq+rr+16nt)
    f32x4 accST[2];
    { f32x4 z = {0.f,0.f,0.f,0.f}; accST[0] = z; accST[1] = z; }
    __builtin_amdgcn_s_setprio(1);
    #pragma unroll
    for (int kc = 0; kc < 4; ++kc) {
      int kq = kc * 4 + lq;
      #pragma unroll
      for (int nt = 0; nt < 2; ++nt) {
        int j = nt * 16 + lr;
        bf16x8 ah = *(const bf16x8*)&rjRM[0][j][kq * 8];
        bf16x8 am = *(const bf16x8*)&rjRM[1][j][kq * 8];
        accST[nt] = mm4(ah, am, riH[kc], riM[kc], accST[nt]);
      }
    }
    __builtin_amdgcn_s_setprio(0);

    // w phase: d2 -> w, 2-split into PV A-fragments (l-term not needed: mm4)
    bf16x8 aH, aM;
    #pragma unroll
    for (int nt = 0; nt < 2; ++nt)
      #pragma unroll
      for (int rr = 0; rr < 4; ++rr) {
        int jl = nt * 16 + 4 * lq + rr;
        int gj = jt * JTILE + jl;
        float d2 = fmaxf(sqi_l_init + sqj_s[jl] - 2.f * accST[nt][rr], 1e-6f);
        float rin = rsqrtf(d2);
        float wgt = mj_s[jl] * rin * rin * rin;
        if (giL == gj) wgt = 0.f;
        wsacc += wgt;
        __bf16 wh = (__bf16)wgt;
        __bf16 wm2 = (__bf16)(wgt - (float)wh);
        int e = nt * 4 + rr;   // slot e: j = 16*nt + 4*lq + rr  (matches jmap)
        aH[e] = wh; aM[e] = wm2;
      }

    // PV: A[i][d] += w @ rj, 4-product, straight-line
    __builtin_amdgcn_s_setprio(1);
    #pragma unroll
    for (int nt = 0; nt < 8; ++nt) {
      int d = nt * 16 + lr;
      bf16x8 bh = *(const bf16x8*)&rjT[0][d][lq * 8];
      bf16x8 bm = *(const bf16x8*)&rjT[1][d][lq * 8];
      accPV[nt] = mm4(aH, aM, bh, bm, accPV[nt]);
    }
    __builtin_amdgcn_s_setprio(0);

    __syncthreads();           // all waves done reading current tile's LDS
    if (more) STORET();        // write prefetched tile (waitcnt lands here)
    __syncthreads();           // next tile's LDS ready
  }

  // ---- peeled epilogue tile: the one attractor tile (slices 0/1), mm6 PV ----
  if (jt < NJTR) {
    f32x4 accST[2];
    { f32x4 z = {0.f,0.f,0.f,0.f}; accST[0] = z; accST[1] = z; }
    #pragma unroll
    for (int kc = 0; kc < 4; ++kc) {
      int kq = kc * 4 + lq;
      #pragma unroll
      for (int nt = 0; nt < 2; ++nt) {
        int j = nt * 16 + lr;
        bf16x8 ah = *(const bf16x8*)&rjRM[0][j][kq * 8];
        bf16x8 am = *(const bf16x8*)&rjRM[1][j][kq * 8];
        accST[nt] = mm4(ah, am, riH[kc], riM[kc], accST[nt]);
      }
    }

    bf16x8 aH, aM, aL;
    #pragma unroll
    for (int nt = 0; nt < 2; ++nt)
      #pragma unroll
      for (int rr = 0; rr < 4; ++rr) {
        int jl = nt * 16 + 4 * lq + rr;
        int gj = jt * JTILE + jl;
        float d2 = fmaxf(sqi_l_init + sqj_s[jl] - 2.f * accST[nt][rr], 1e-6f);
        float rin = rsqrtf(d2);
        float wgt = mj_s[jl] * rin * rin * rin;
        if (giL == gj) wgt = 0.f;
        wsacc += wgt;
        __bf16 wh, wm2, wl2; split3(wgt, wh, wm2, wl2);
        int e = nt * 4 + rr;
        aH[e] = wh; aM[e] = wm2; aL[e] = wl2;
      }

    #pragma unroll
    for (int nt = 0; nt < 8; ++nt) {
      int d = nt * 16 + lr;
      bf16x8 bh = *(const bf16x8*)&rjT[0][d][lq * 8];
      bf16x8 bm = *(const bf16x8*)&rjT[1][d][lq * 8];
      bf16x8 bl = *(const bf16x8*)&rjT[2][d][lq * 8];
      accPV[nt] = mm6(aH, aM, aL, bh, bm, bl, accPV[nt]);
    }
  }

  // ---- epilogue stores ----
  {
    float val = wsacc;
    val += __shfl_xor(val, 16);
    val += __shfl_xor(val, 32);
    int gi = bi0 + wv * 16 + lr;
    if (lane < 16 && gi < NROW) wsump[(size_t)slice * NROW + gi] = val;
  }
  #pragma unroll
  for (int nt = 0; nt < 8; ++nt)
    #pragma unroll
    for (int rr = 0; rr < 4; ++rr) {
      int gi = bi0 + wv * 16 + 4 * lq + rr;
      int d = nt * 16 + lr;
      if (gi < NROW) apart[((size_t)slice * NROW + gi) * DIM + d] = accPV[nt][rr];
    }
}

// ---------------- mlp: integrate + boundary + Hamiltonian + damp/clip + SPLIT EMIT ----------------
__global__ __launch_bounds__(256)
void k_mlp(float* __restrict__ r, float* __restrict__ v, float* __restrict__ sq,
           const float* __restrict__ apart, const float* __restrict__ wsump,
           const __bf16* __restrict__ wb1t, const __bf16* __restrict__ wb2t,
           const __bf16* __restrict__ wb3t,
           const __bf16* __restrict__ wp1t, const __bf16* __restrict__ wp1r,
           const __bf16* __restrict__ wk1t, const __bf16* __restrict__ wk1r,
           const float* __restrict__ bb1, const float* __restrict__ bb2,
           const float* __restrict__ bb3,
           const float* __restrict__ pb1, const float* __restrict__ pw2,
           const float* __restrict__ kb1, const float* __restrict__ kw2,
           __bf16* __restrict__ rh, __bf16* __restrict__ rm,
           __bf16* __restrict__ rth, __bf16* __restrict__ rtm,
           __bf16* __restrict__ rtl,
           int do_ham)
{
  __shared__ __align__(16) float  Cf[WR][264];          // [r | v] f32 master
  __shared__ __align__(16) __bf16 Csp[3][WR][264];      // C 3-split (reused as split scratch)
  __shared__ __align__(16) __bf16 Hsp[2][3][WR][72];    // hidden 3-split, dbuf
  __shared__ __align__(16) __bf16 Gsp[3][WR][264];      // ham (1-t^2)*w2 3-split

  const int tid = threadIdx.x;
  const int wv = tid >> 6, lane = tid & 63;
  const int lq = lane >> 4, lr = lane & 15;

  // ---------- phase A: reduce apart, integrate, stage C ----------
  {
    const int row = tid >> 4, c = tid & 15;
    const int grow = blockIdx.x * WR + row;
    const int gsrc = grow < NROW ? grow : 0;
    float s[8] = {0.f,0.f,0.f,0.f,0.f,0.f,0.f,0.f};
    float wsv = 0.f;
    #pragma unroll
    for (int sl = 0; sl < NSLICE; ++sl) {
      const float4* ap4 = (const float4*)&apart[((size_t)sl * NROW + gsrc) * DIM + c * 8];
      float4 t0 = ap4[0], t1 = ap4[1];
      s[0] += t0.x; s[1] += t0.y; s[2] += t0.z; s[3] += t0.w;
      s[4] += t1.x; s[5] += t1.y; s[6] += t1.z; s[7] += t1.w;
      wsv += wsump[(size_t)sl * NROW + gsrc];
    }
    const float4* r4 = (const float4*)&r[(size_t)gsrc * DIM + c * 8];
    const float4* v4 = (const float4*)&v[(size_t)gsrc * DIM + c * 8];
    float4 ra = r4[0], rb = r4[1], va = v4[0], vb = v4[1];
    float re[8] = {ra.x,ra.y,ra.z,ra.w, rb.x,rb.y,rb.z,rb.w};
    float ve[8] = {va.x,va.y,va.z,va.w, vb.x,vb.y,vb.z,vb.w};
    bf16x8 rh8, rm8, rl8, vh8, vm8, vl8;
    #pragma unroll
    for (int e = 0; e < 8; ++e) {
      float a = 1e-3f * (s[e] - wsv * re[e]);
      float vn = ve[e] + 0.1f * a;
      float rn = re[e] + 0.1f * vn;
      Cf[row][c * 8 + e] = rn;
      Cf[row][128 + c * 8 + e] = vn;
      __bf16 h, m, l;
      split3(rn, h, m, l); rh8[e] = h; rm8[e] = m; rl8[e] = l;
      split3(vn, h, m, l); vh8[e] = h; vm8[e] = m; vl8[e] = l;
    }
    *(bf16x8*)&Csp[0][row][c * 8] = rh8; *(bf16x8*)&Csp[0][row][128 + c * 8] = vh8;
    *(bf16x8*)&Csp[1][row][c * 8] = rm8; *(bf16x8*)&Csp[1][row][128 + c * 8] = vm8;
    *(bf16x8*)&Csp[2][row][c * 8] = rl8; *(bf16x8*)&Csp[2][row][128 + c * 8] = vl8;
  }
  __syncthreads();

  // ---------- L1: H1 = tanh(C @ bw1 + bb1) ----------
  {
    f32x4 acc = {0.f, 0.f, 0.f, 0.f};
    const __bf16* b = wb1t + ((size_t)(wv * 16 + lr)) * 256;
    #pragma unroll
    for (int kc = 0; kc < 8; ++kc) {
      int k0 = kc * 32 + lq * 8;
      bf16x8 ah = *(const bf16x8*)&Csp[0][lr][k0];
      bf16x8 am = *(const bf16x8*)&Csp[1][lr][k0];
      bf16x8 al = *(const bf16x8*)&Csp[2][lr][k0];
      bf16x8 b0 = *(const bf16x8*)&b[k0];
      bf16x8 b1 = *(const bf16x8*)&b[16384 + k0];
      bf16x8 b2 = *(const bf16x8*)&b[32768 + k0];
      acc = mm6(ah, am, al, b0, b1, b2, acc);
    }
    int n = wv * 16 + lr;
    float bias = bb1[n];
    #pragma unroll
    for (int reg = 0; reg < 4; ++reg) {
      int i = 4 * lq + reg;
      float h1 = tanhf(acc[reg] + bias);
      __bf16 h, m, l; split3(h1, h, m, l);
      Hsp[0][0][i][n] = h; Hsp[0][1][i][n] = m; Hsp[0][2][i][n] = l;
    }
  }
  __syncthreads();

  // ---------- L2: H2 = tanh(H1 @ bw2 + bb2) ----------
  {
    f32x4 acc = {0.f, 0.f, 0.f, 0.f};
    const __bf16* b = wb2t + ((size_t)(wv * 16 + lr)) * 64;
    #pragma unroll
    for (int kc = 0; kc < 2; ++kc) {
      int k0 = kc * 32 + lq * 8;
      bf16x8 ah = *(const bf16x8*)&Hsp[0][0][lr][k0];
      bf16x8 am = *(const bf16x8*)&Hsp[0][1][lr][k0];
      bf16x8 al = *(const bf16x8*)&Hsp[0][2][lr][k0];
      bf16x8 b0 = *(const bf16x8*)&b[k0];
      bf16x8 b1 = *(const bf16x8*)&b[4096 + k0];
      bf16x8 b2 = *(const bf16x8*)&b[8192 + k0];
      acc = mm6(ah, am, al, b0, b1, b2, acc);
    }
    int n = wv * 16 + lr;
    float bias = bb2[n];
    #pragma unroll
    for (int reg = 0; reg < 4; ++reg) {
      int i = 4 * lq + reg;
      float h2 = tanhf(acc[reg] + bias);
      __bf16 h, m, l; split3(h2, h, m, l);
      Hsp[1][0][i][n] = h; Hsp[1][1][i][n] = m; Hsp[1][2][i][n] = l;
    }
  }
  __syncthreads();

  // ---------- L3: r += 0.1*tanh(H2 @ bw3 + bb3) ----------
  {
    f32x4 acc[2];
    { f32x4 z = {0.f,0.f,0.f,0.f}; acc[0] = z; acc[1] = z; }
    #pragma unroll
    for (int kc = 0; kc < 2; ++kc) {
      int k0 = kc * 32 + lq * 8;
      bf16x8 ah = *(const bf16x8*)&Hsp[1][0][lr][k0];
      bf16x8 am = *(const bf16x8*)&Hsp[1][1][lr][k0];
      bf16x8 al = *(const bf16x8*)&Hsp[1][2][lr][k0];
      #pragma unroll
      for (int t = 0; t < 2; ++t) {
        const __bf16* b = wb3t + ((size_t)(t * 64 + wv * 16 + lr)) * 64;
        bf16x8 b0 = *(const bf16x8*)&b[k0];
        bf16x8 b1 = *(const bf16x8*)&b[8192 + k0];
        bf16x8 b2 = *(const bf16x8*)&b[16384 + k0];
        acc[t] = mm6(ah, am, al, b0, b1, b2, acc[t]);
      }
    }
    #pragma unroll
    for (int t = 0; t < 2; ++t) {
      int n = t * 64 + wv * 16 + lr;
      float bias = bb3[n];
      #pragma unroll
      for (int reg = 0; reg < 4; ++reg) {
        int i = 4 * lq + reg;
        float o = tanhf(acc[t][reg] + bias);
        float rn = Cf[i][n] + 0.1f * o;
        Cf[i][n] = rn;
        __bf16 h, m, l; split3(rn, h, m, l);
        Csp[0][i][n] = h; Csp[1][i][n] = m; Csp[2][i][n] = l;
      }
    }
  }
  __syncthreads();

  if (do_ham) {
    // ---- potential forward: G = (1-tanh^2(Cr@pw1+pb1))*pw2 ----
    {
      f32x4 acc[4];
      #pragma unroll
      for (int t = 0; t < 4; ++t) { f32x4 z = {0.f,0.f,0.f,0.f}; acc[t] = z; }
      #pragma unroll
      for (int kc = 0; kc < 4; ++kc) {
        int k0 = kc * 32 + lq * 8;
        bf16x8 ah = *(const bf16x8*)&Csp[0][lr][k0];
        bf16x8 am = *(const bf16x8*)&Csp[1][lr][k0];
        bf16x8 al = *(const bf16x8*)&Csp[2][lr][k0];
        #pragma unroll
        for (int t = 0; t < 4; ++t) {
          const __bf16* b = wp1t + ((size_t)(t * 64 + wv * 16 + lr)) * 128;
          bf16x8 b0 = *(const bf16x8*)&b[k0];
          bf16x8 b1 = *(const bf16x8*)&b[32768 + k0];
          bf16x8 b2 = *(const bf16x8*)&b[65536 + k0];
          acc[t] = mm6(ah, am, al, b0, b1, b2, acc[t]);
        }
      }
      #pragma unroll
      for (int t = 0; t < 4; ++t) {
        int n = t * 64 + wv * 16 + lr;
        float pb = pb1[n], pws = pw2[n];
        #pragma unroll
        for (int reg = 0; reg < 4; ++reg) {
          int i = 4 * lq + reg;
          float tt = tanhf(acc[t][reg] + pb);
          float g = (1.f - tt * tt) * pws;
          __bf16 h, m, l; split3(g, h, m, l);
          Gsp[0][i][n] = h; Gsp[1][i][n] = m; Gsp[2][i][n] = l;
        }
      }
    }
    __syncthreads();
    // ---- potential grad: r -= 0.01 * (G @ pw1 rows) ----
    {
      f32x4 acc[2];
      { f32x4 z = {0.f,0.f,0.f,0.f}; acc[0] = z; acc[1] = z; }
      #pragma unroll
      for (int kc = 0; kc < 8; ++kc) {
        int k0 = kc * 32 + lq * 8;
        bf16x8 ah = *(const bf16x8*)&Gsp[0][lr][k0];
        bf16x8 am = *(const bf16x8*)&Gsp[1][lr][k0];
        bf16x8 al = *(const bf16x8*)&Gsp[2][lr][k0];
        #pragma unroll
        for (int t = 0; t < 2; ++t) {
          const __bf16* b = wp1r + ((size_t)(t * 64 + wv * 16 + lr)) * 256;
          bf16x8 b0 = *(const bf16x8*)&b[k0];
          bf16x8 b1 = *(const bf16x8*)&b[32768 + k0];
          bf16x8 b2 = *(const bf16x8*)&b[65536 + k0];
          acc[t] = mm6(ah, am, al, b0, b1, b2, acc[t]);
        }
      }
      #pragma unroll
      for (int t = 0; t < 2; ++t)
        #pragma unroll
        for (int reg = 0; reg < 4; ++reg) {
          int i = 4 * lq + reg, d = t * 64 + wv * 16 + lr;
          float rn = Cf[i][d] - 0.01f * acc[t][reg];
          Cf[i][d] = rn;
          __bf16 h, m, l; split3(rn, h, m, l);
          Csp[0][i][d] = h; Csp[1][i][d] = m; Csp[2][i][d] = l;
        }
    }
    __syncthreads();
    // ---- kinetic forward on v ----
    {
      f32x4 acc[4];
      #pragma unroll
      for (int t = 0; t < 4; ++t) { f32x4 z = {0.f,0.f,0.f,0.f}; acc[t] = z; }
      #pragma unroll
      for (int kc = 0; kc < 4; ++kc) {
        int k0 = 128 + kc * 32 + lq * 8;
        bf16x8 ah = *(const bf16x8*)&Csp[0][lr][k0];
        bf16x8 am = *(const bf16x8*)&Csp[1][lr][k0];
        bf16x8 al = *(const bf16x8*)&Csp[2][lr][k0];
        #pragma unroll
        for (int t = 0; t < 4; ++t) {
          const __bf16* b = wk1t + ((size_t)(t * 64 + wv * 16 + lr)) * 128;
          int kb = kc * 32 + lq * 8;
          bf16x8 b0 = *(const bf16x8*)&b[kb];
          bf16x8 b1 = *(const bf16x8*)&b[32768 + kb];
          bf16x8 b2 = *(const bf16x8*)&b[65536 + kb];
          acc[t] = mm6(ah, am, al, b0, b1, b2, acc[t]);
        }
      }
      #pragma unroll
      for (int t = 0; t < 4; ++t) {
        int n = t * 64 + wv * 16 + lr;
        float kb = kb1[n], kws = kw2[n];
        #pragma unroll
        for (int reg = 0; reg < 4; ++reg) {
          int i = 4 * lq + reg;
          float tt = tanhf(acc[t][reg] + kb);
          float g = (1.f - tt * tt) * kws;
          __bf16 h, m, l; split3(g, h, m, l);
          Gsp[0][i][n] = h; Gsp[1][i][n] = m; Gsp[2][i][n] = l;
        }
      }
    }
    __syncthreads();
    // ---- kinetic grad: v += 0.01 * (G @ kw1 rows) ----
    {
      f32x4 acc[2];
      { f32x4 z = {0.f,0.f,0.f,0.f}; acc[0] = z; acc[1] = z; }
      #pragma unroll
      for (int kc = 0; kc < 8; ++kc) {
        int k0 = kc * 32 + lq * 8;
        bf16x8 ah = *(const bf16x8*)&Gsp[0][lr][k0];
        bf16x8 am = *(const bf16x8*)&Gsp[1][lr][k0];
        bf16x8 al = *(const bf16x8*)&Gsp[2][lr][k0];
        #pragma unroll
        for (int t = 0; t < 2; ++t) {
          const __bf16* b = wk1r + ((size_t)(t * 64 + wv * 16 + lr)) * 256;
          bf16x8 b0 = *(const bf16x8*)&b[k0];
          bf16x8 b1 = *(const bf16x8*)&b[32768 + k0];
          bf16x8 b2 = *(const bf16x8*)&b[65536 + k0];
          acc[t] = mm6(ah, am, al, b0, b1, b2, acc[t]);
        }
      }
      #pragma unroll
      for (int t = 0; t < 2; ++t)
        #pragma unroll
        for (int reg = 0; reg < 4; ++reg) {
          int i = 4 * lq + reg, d = t * 64 + wv * 16 + lr;
          Cf[i][128 + d] += 0.01f * acc[t][reg];
        }
    }
    __syncthreads();
  }

  // ---------- phase F: damp, clip, writeback + fused split (row-major + stage) ----------
  {
    const int row = tid >> 4, c = tid & 15;
    const int grow = blockIdx.x * WR + row;
    float re[8], ve[8];
    #pragma unroll
    for (int e = 0; e < 8; ++e) {
      re[e] = Cf[row][c * 8 + e];
      ve[e] = Cf[row][128 + c * 8 + e] * 0.95f;
    }
    float n2 = 0.f;
    #pragma unroll
    for (int e = 0; e < 8; ++e) n2 += re[e] * re[e];
    n2 += __shfl_xor(n2, 1); n2 += __shfl_xor(n2, 2);
    n2 += __shfl_xor(n2, 4); n2 += __shfl_xor(n2, 8);
    float nrm = sqrtf(n2);
    float sc = fminf(1.f, 10.f / fmaxf(nrm, 1e-12f));
    float rs[8];
    #pragma unroll
    for (int e = 0; e < 8; ++e) rs[e] = re[e] * sc;
    bf16x8 h8, m8, l8;
    #pragma unroll
    for (int e = 0; e < 8; ++e) {
      __bf16 h, m, l; split3(rs[e], h, m, l);
      h8[e] = h; m8[e] = m; l8[e] = l;
    }
    // stage splits for transpose (all rows; pads guarded at write)
    *(bf16x8*)&Csp[0][row][c * 8] = h8;
    *(bf16x8*)&Csp[1][row][c * 8] = m8;
    *(bf16x8*)&Csp[2][row][c * 8] = l8;
    if (grow < NROW) {
      float4 o0, o1, w0, w1;
      o0.x = rs[0]; o0.y = rs[1]; o0.z = rs[2]; o0.w = rs[3];
      o1.x = rs[4]; o1.y = rs[5]; o1.z = rs[6]; o1.w = rs[7];
      w0.x = ve[0]; w0.y = ve[1]; w0.z = ve[2]; w0.w = ve[3];
      w1.x = ve[4]; w1.y = ve[5]; w1.z = ve[6]; w1.w = ve[7];
      *(float4*)&r[(size_t)grow * DIM + c * 8] = o0;
      *(float4*)&r[(size_t)grow * DIM + c * 8 + 4] = o1;
      *(float4*)&v[(size_t)grow * DIM + c * 8] = w0;
      *(float4*)&v[(size_t)grow * DIM + c * 8 + 4] = w1;
      *(bf16x8*)&rh[(size_t)grow * DIM + c * 8] = h8;
      *(bf16x8*)&rm[(size_t)grow * DIM + c * 8] = m8;
      if (c == 0) sq[grow] = n2 * sc * sc;
    }
  }
  __syncthreads();
  // ---------- transposed j-permuted split emit (targets this block's 16 j's) ----------
  {
    const int grow0 = blockIdx.x * WR;
    const int b32 = grow0 >> 5;
    const int half = blockIdx.x & 1;          // which 16-half of the 32-block
    for (int u = tid; u < 384; u += 256) {
      int s = u >> 7, d = u & 127;
      __bf16* dst = (s == 0 ? rth : (s == 1 ? rtm : rtl))
                    + (size_t)d * MP + b32 * 32 + half * 4;
      #pragma unroll
      for (int a = 0; a < 4; ++a) {
        if (grow0 + 4 * a + 4 <= NROW) {      // a-group fully real (NROW%16==8 -> aligned)
          bf16x4 q;
          #pragma unroll
          for (int c2 = 0; c2 < 4; ++c2) q[c2] = Csp[s][4 * a + c2][d];
          *(bf16x4*)&dst[a * 8] = q;
        }
      }
    }
  }
}

// ---------------- feature kernels ----------------
__global__ void k_statinit(double* pd_sum, double* pd_sumsq,
                           unsigned* pd_min, unsigned* pd_max)
{
  if (threadIdx.x == 0) {
    *pd_sum = 0.0; *pd_sumsq = 0.0;
    *pd_min = 0x7f7fffffu;
    *pd_max = 0u;
  }
}

__global__ __launch_bounds__(256)
void k_com(const float* __restrict__ r, const float* __restrict__ am,
           float* __restrict__ feat)
{
  int b = blockIdx.x, ch = blockIdx.y;
  int c = threadIdx.x & 31, rg = threadIdx.x >> 5;
  int col = ch * 32 + c;
  __shared__ float red[8][33];
  float amsum = 0.f;
  for (int k = 0; k < 10; ++k) amsum += am[k];
  float tot = 1024.f + amsum;

  float s = 0.f;
  #pragma unroll 4
  for (int p = rg; p < NPTS; p += 8) {
    int row = p < 1024 ? b * 1024 + p : NPART + b * 10 + (p - 1024);
    float m = p < 1024 ? 1.f : am[p - 1024];
    s += m * r[(size_t)row * DIM + col];
  }
  red[rg][c] = s; __syncthreads();
  for (int h = 4; h >= 1; h >>= 1) { if (rg < h) red[rg][c] += red[rg + h][c]; __syncthreads(); }
  float com = red[0][c] / tot;
  __syncthreads();

  float s2 = 0.f, s3 = 0.f;
  #pragma unroll 4
  for (int p = rg; p < NPTS; p += 8) {
    int row = p < 1024 ? b * 1024 + p : NPART + b * 10 + (p - 1024);
    float cc = r[(size_t)row * DIM + col] - com;
    s2 += cc * cc; s3 += cc * cc * cc;
  }
  red[rg][c] = s2; __syncthreads();
  for (int h = 4; h >= 1; h >>= 1) { if (rg < h) red[rg][c] += red[rg + h][c]; __syncthreads(); }
  float var = red[0][c] / 1034.f;
  __syncthreads();
  red[rg][c] = s3; __syncthreads();
  for (int h = 4; h >= 1; h >>= 1) { if (rg < h) red[rg][c] += red[rg + h][c]; __syncthreads(); }
  float skw = red[0][c] / 1034.f;
  if (rg == 0) {
    feat[b * 384 + col]       = com;
    feat[b * 384 + 128 + col] = var;
    feat[b * 384 + 256 + col] = skw;
  }
}

__global__ __launch_bounds__(256)
void k_pdist(const float* __restrict__ r, const float* __restrict__ sq,
             double* pd_sum, double* pd_sumsq, unsigned* pd_min, unsigned* pd_max)
{
  int ta = blockIdx.x, tb = blockIdx.y;
  if (ta > tb) return;
  __shared__ __align__(16) float pa_s[64 * DIM];
  __shared__ __align__(16) float pb_s[64 * DIM];
  __shared__ float sqa_s[64], sqb_s[64];
  const int tid = threadIdx.x;
  const int tx = tid & 15, ty = tid >> 4;

  #pragma unroll
  for (int p = 0; p < 8; ++p) {
    int q = tid + p * 256;
    int row = q >> 5, slot = q & 31;
    int pidx = ta * 64 + row;
    float4 val = make_float4(0.f, 0.f, 0.f, 0.f);
    if (pidx < NPTS) {
      int srow = pidx < 1024 ? pidx : (NPART + pidx - 1024);
      val = *(const float4*)&r[(size_t)srow * DIM + slot * 4];
    }
    *(float4*)&pa_s[lds_off(row, slot)] = val;
    pidx = tb * 64 + row;
    val = make_float4(0.f, 0.f, 0.f, 0.f);
    if (pidx < NPTS) {
      int srow = pidx < 1024 ? pidx : (NPART + pidx - 1024);
      val = *(const float4*)&r[(size_t)srow * DIM + slot * 4];
    }
    *(float4*)&pb_s[lds_off(row, slot)] = val;
  }
  if (tid < 64) {
    int pidx = ta * 64 + tid;
    sqa_s[tid] = pidx < NPTS ? sq[pidx < 1024 ? pidx : NPART + pidx - 1024] : 0.f;
  } else if (tid < 128) {
    int t2 = tid - 64;
    int pidx = tb * 64 + t2;
    sqb_s[t2] = pidx < NPTS ? sq[pidx < 1024 ? pidx : NPART + pidx - 1024] : 0.f;
  }
  __syncthreads();

  const int swi = ty & 7, swj = tx & 7;
  float sv[4][4] = {};
  #pragma unroll 8
  for (int ks = 0; ks < 32; ++ks) {
    int oi = (ks ^ swi) << 2, oj = (ks ^ swj) << 2;
    float4 av[4], bv[4];
    #pragma unroll
    for (int a = 0; a < 4; ++a) av[a] = *(const float4*)&pa_s[(ty * 4 + a) * DIM + oi];
    #pragma unroll
    for (int b = 0; b < 4; ++b) bv[b] = *(const float4*)&pb_s[(tx * 4 + b) * DIM + oj];
    #pragma unroll
    for (int a = 0; a < 4; ++a)
      #pragma unroll
      for (int b = 0; b < 4; ++b) sv[a][b] = dot4acc(sv[a][b], av[a], bv[b]);
  }

  double tsum = 0.0, tsq = 0.0;
  float tmn = 3.402823466e38f, tmx = 0.f;
  #pragma unroll
  for (int a = 0; a < 4; ++a)
    #pragma unroll
    for (int b = 0; b < 4; ++b) {
      int ga = ta * 64 + ty * 4 + a;
      int gb = tb * 64 + tx * 4 + b;
      float d2 = sqa_s[ty * 4 + a] + sqb_s[tx * 4 + b] - 2.f * sv[a][b];
      float dist = sqrtf(fmaxf(d2, 0.f));
      bool ok = (ga < NPTS) && (gb < NPTS) && ((ta != tb) || (ga < gb));
      if (ok) {
        tsum += (double)dist;
        tsq  += (double)dist * (double)dist;
        tmn = fminf(tmn, dist);
        tmx = fmaxf(tmx, dist);
      }
    }
  for (int mk = 1; mk < 64; mk <<= 1) {
    tsum += __shfl_xor(tsum, mk);
    tsq  += __shfl_xor(tsq, mk);
    tmn = fminf(tmn, __shfl_xor(tmn, mk));
    tmx = fmaxf(tmx, __shfl_xor(tmx, mk));
  }
  if ((tid & 63) == 0) {
    atomicAdd(pd_sum, tsum);
    atomicAdd(pd_sumsq, tsq);
    atomicMin(pd_min, __float_as_uint(tmn));
    atomicMax(pd_max, __float_as_uint(tmx));
  }
}

__global__ void k_proj(const float* __restrict__ feat,
                       const double* pd_sum, const double* pd_sumsq,
                       const unsigned* pd_min, const unsigned* pd_max,
                       const float* __restrict__ fw, const float* __restrict__ fb,
                       float* __restrict__ out)
{
  int t = threadIdx.x;
  int b = t >> 7, d = t & 127;
  double sm = *pd_sum, s2 = *pd_sumsq;
  double mean = sm / NPAIRS;
  double var = (s2 - sm * sm / NPAIRS) / (NPAIRS - 1.0);
  float sd = (float)sqrt(var > 0.0 ? var : 0.0);
  float mn = __uint_as_float(*pd_min);
  float mx = __uint_as_float(*pd_max);
  float acc0 = fb[d], acc1 = 0.f, acc2 = 0.f, acc3 = 0.f;
  #pragma unroll 8
  for (int f = 0; f < 384; f += 4) {
    acc0 = fmaf(feat[b * 384 + f + 0], fw[(f + 0) * 128 + d], acc0);
    acc1 = fmaf(feat[b * 384 + f + 1], fw[(f + 1) * 128 + d], acc1);
    acc2 = fmaf(feat[b * 384 + f + 2], fw[(f + 2) * 128 + d], acc2);
    acc3 = fmaf(feat[b * 384 + f + 3], fw[(f + 3) * 128 + d], acc3);
  }
  float acc = (acc0 + acc1) + (acc2 + acc3);
  acc = fmaf((float)mean, fw[384 * 128 + d], acc);
  acc = fmaf(sd,          fw[385 * 128 + d], acc);
  acc = fmaf(mn,          fw[386 * 128 + d], acc);
  acc = fmaf(mx,          fw[387 * 128 + d], acc);
  out[b * 128 + d] = acc;
}

extern "C" void kernel_launch(void* const* d_in, const int* in_sizes, int n_in,
                              void* d_out, int out_size, void* d_ws, size_t ws_size,
                              hipStream_t stream) {
  (void)in_sizes; (void)n_in; (void)out_size; (void)ws_size;
  const float* x   = (const float*)d_in[0];
  const float* ap  = (const float*)d_in[1];
  const float* am  = (const float*)d_in[2];
  const float* v0  = (const float*)d_in[3];
  const float* pw1 = (const float*)d_in[4];
  const float* pb1 = (const float*)d_in[5];
  const float* pw2 = (const float*)d_in[6];
  const float* kw1 = (const float*)d_in[8];
  const float* kb1 = (const float*)d_in[9];
  const float* kw2 = (const float*)d_in[10];
  const float* bw1 = (const float*)d_in[12];
  const float* bb1 = (const float*)d_in[13];
  const float* bw2 = (const float*)d_in[14];
  const float* bb2 = (const float*)d_in[15];
  const float* bw3 = (const float*)d_in[16];
  const float* bb3 = (const float*)d_in[17];
  const float* fw  = (const float*)d_in[18];
  const float* fb  = (const float*)d_in[19];

  // workspace layout (bytes), 16B-aligned; same extents as rounds 5-15
  char* ws = (char*)d_ws;
  double*   pd_sum   = (double*)(ws + 0);
  double*   pd_sumsq = (double*)(ws + 8);
  unsigned* pd_min   = (unsigned*)(ws + 16);
  unsigned* pd_max   = (unsigned*)(ws + 20);
  float*    feat     = (float*)(ws + 32);        // 4*384 f32
  float*    r        = (float*)(ws + 6176);      // MP*128 f32
  float*    v        = (float*)(ws + 2168864);   // MP*128 f32
  float*    sq       = (float*)(ws + 4331552);   // MP f32
  float*    wsump    = (float*)(ws + 4348448);   // NSLICE*NROW f32
  float*    apart    = (float*)(ws + 4480800);   // NSLICE*NROW*128 f32
  __bf16*   rh       = (__bf16*)(ws + 21421856); // MP*128 bf16
  __bf16*   rm       = (__bf16*)(ws + 22503200);
  // (ws + 23584544: former rl slot, unused)
  __bf16*   rth      = (__bf16*)(ws + 24665888); // 128*MP bf16 (transposed, j-permuted)
  __bf16*   rtm      = (__bf16*)(ws + 25747232);
  __bf16*   rtl      = (__bf16*)(ws + 26828576); // ends 27909920
  // pre-split weights (h|m|l planes packed per array)
  __bf16*   wb1t     = (__bf16*)(ws + 27909920); // 3*16384
  __bf16*   wb2t     = (__bf16*)(ws + 28008224); // 3*4096
  __bf16*   wb3t     = (__bf16*)(ws + 28032800); // 3*8192
  __bf16*   wp1t     = (__bf16*)(ws + 28081952); // 3*32768
  __bf16*   wp1r     = (__bf16*)(ws + 28278560); // 3*32768
  __bf16*   wk1t     = (__bf16*)(ws + 28475168); // 3*32768
  __bf16*   wk1r     = (__bf16*)(ws + 28671776); // 3*32768 -> ends 28868384

  k_wprep<<<dim3(128, 7), 256, 0, stream>>>(bw1, bw2, bw3, pw1, kw1,
                                            wb1t, wb2t, wb3t, wp1t, wp1r, wk1t, wk1r);
  k_init<<<MP / 4, 256, 0, stream>>>(x, ap, am, v0, r, v, sq);
  // one-time full split (covers all 4224 rows; pads become zeros and stay zero)
  k_split<<<MP / 32, 256, 0, stream>>>(r, rh, rm, rth, rtm, rtl);
  for (int it = 0; it < NITER; ++it) {
    // grid (slice, itile): flat_wg % 8 == slice -> per-slice j-stream is XCD-local
    k_force<<<dim3(NSLICE, NIBR), 256, 0, stream>>>(rh, rm, rth, rtm, rtl,
                                                    sq, am, apart, wsump);
    k_mlp<<<NMLPB, 256, 0, stream>>>(r, v, sq, apart, wsump,
        wb1t, wb2t, wb3t, wp1t, wp1r, wk1t, wk1r,
        bb1, bb2, bb3, pb1, pw2, kb1, kw2,
        rh, rm, rth, rtm, rtl,
        (it % 5) == 0 ? 1 : 0);
  }
  k_statinit<<<1, 64, 0, stream>>>(pd_sum, pd_sumsq, pd_min, pd_max);
  k_com<<<dim3(4, 4), 256, 0, stream>>>(r, am, feat);
  k_pdist<<<dim3(17, 17), 256, 0, stream>>>(r, sq, pd_sum, pd_sumsq, pd_min, pd_max);
  k_proj<<<1, 512, 0, stream>>>(feat, pd_sum, pd_sumsq, pd_min, pd_max, fw, fb,
                                (float*)d_out);
}